// Round 3
// baseline (789.785 us; speedup 1.0000x reference)
//
#include <hip/hip_runtime.h>

#define IN_DIM 256
#define HID 64
#define HEADS 4
#define C1 256   // HID*HEADS

// ---------------------------------------------------------------------------
// CSR build: histogram of dst -> exclusive scan -> atomic fill of (src,dst)
// ---------------------------------------------------------------------------

__global__ __launch_bounds__(256) void zero_int_kernel(int* __restrict__ p, int n) {
  int i = blockIdx.x * 256 + threadIdx.x;
  if (i < n) p[i] = 0;
}

__global__ __launch_bounds__(256) void hist_kernel(const int* __restrict__ ei,
                                                   int E, int N, int* __restrict__ counts) {
  int e = blockIdx.x * 256 + threadIdx.x;
  if (e >= E + N) return;
  int dst = (e < E) ? ei[(size_t)E + e] : (e - E);
  atomicAdd(&counts[dst], 1);
}

__global__ __launch_bounds__(1024) void scan_kernel(const int* __restrict__ counts,
                                                    int* __restrict__ indptr,
                                                    int* __restrict__ fillpos, int N) {
  __shared__ int sdata[1024];
  int tid = threadIdx.x;
  int running = 0;
  for (int base = 0; base < N; base += 1024) {
    int v = (base + tid < N) ? counts[base + tid] : 0;
    sdata[tid] = v;
    __syncthreads();
    for (int off = 1; off < 1024; off <<= 1) {
      int t = (tid >= off) ? sdata[tid - off] : 0;
      __syncthreads();
      sdata[tid] += t;
      __syncthreads();
    }
    int excl = sdata[tid] - v;
    if (base + tid < N) {
      indptr[base + tid] = running + excl;
      fillpos[base + tid] = running + excl;
    }
    int total = sdata[1023];
    __syncthreads();
    running += total;
  }
  if (tid == 0) indptr[N] = running;
}

__global__ __launch_bounds__(256) void fill_kernel(const int* __restrict__ ei, int E, int N,
                                                   int* __restrict__ fillpos,
                                                   int* __restrict__ srcs,
                                                   int* __restrict__ edst) {
  int e = blockIdx.x * 256 + threadIdx.x;
  if (e >= E + N) return;
  int src, dst;
  if (e < E) { src = ei[e]; dst = ei[(size_t)E + e]; }
  else       { src = e - E; dst = e - E; }
  int pos = atomicAdd(&fillpos[dst], 1);
  srcs[pos] = src;
  edst[pos] = dst;
}

// ---------------------------------------------------------------------------
// Tiled f32 GEMM: C[M,NC] = A[M,K] @ B[K,NC]   (BM=BN=64, BK=32, 4x4 micro)
// ---------------------------------------------------------------------------

__global__ __launch_bounds__(256) void gemm_kernel(const float* __restrict__ A,
                                                   const float* __restrict__ B,
                                                   float* __restrict__ C,
                                                   int M, int NC, int K) {
  const int BM = 64, BN = 64, BK = 32, TM = 4, TN = 4;
  __shared__ float As[BK][BM + 4];
  __shared__ float Bs[BK][BN + 4];
  int bm = blockIdx.x * BM;
  int bn = blockIdx.y * BN;
  int tid = threadIdx.x;
  int tr = tid >> 4;   // 0..15
  int tc = tid & 15;   // 0..15
  float acc[TM][TN] = {};
  for (int k0 = 0; k0 < K; k0 += BK) {
    #pragma unroll
    for (int it = 0; it < (BM * BK) / 256; ++it) {
      int i = tid + it * 256;
      int r = i >> 5, c = i & 31;
      int row = bm + r;
      As[c][r] = (row < M) ? A[(size_t)row * K + k0 + c] : 0.f;
    }
    #pragma unroll
    for (int it = 0; it < (BK * BN) / 256; ++it) {
      int i = tid + it * 256;
      int r = i >> 6, c = i & 63;
      Bs[r][c] = B[(size_t)(k0 + r) * NC + bn + c];
    }
    __syncthreads();
    #pragma unroll
    for (int k = 0; k < BK; ++k) {
      float a[TM], b[TN];
      #pragma unroll
      for (int i = 0; i < TM; ++i) a[i] = As[k][tr * TM + i];
      #pragma unroll
      for (int j = 0; j < TN; ++j) b[j] = Bs[k][tc * TN + j];
      #pragma unroll
      for (int i = 0; i < TM; ++i)
        #pragma unroll
        for (int j = 0; j < TN; ++j)
          acc[i][j] += a[i] * b[j];
    }
    __syncthreads();
  }
  #pragma unroll
  for (int i = 0; i < TM; ++i) {
    int row = bm + tr * TM + i;
    if (row < M) {
      #pragma unroll
      for (int j = 0; j < TN; ++j)
        C[(size_t)row * NC + bn + tc * TN + j] = acc[i][j];
    }
  }
}

// ---------------------------------------------------------------------------
// Attention logit projections
// ---------------------------------------------------------------------------

__global__ __launch_bounds__(256) void alpha1_kernel(const float* __restrict__ H1,
                                                     const float* __restrict__ a_src,
                                                     const float* __restrict__ a_dst,
                                                     float* __restrict__ asrc,
                                                     float* __restrict__ adst, int N) {
  int g = blockIdx.x * 4 + (threadIdx.x >> 6);   // group id over N*HEADS
  int lane = threadIdx.x & 63;
  int n = g >> 2, h = g & 3;
  if (n >= N) return;
  float hv = H1[(size_t)n * C1 + h * HID + lane];
  float vs = hv * a_src[h * HID + lane];
  float vd = hv * a_dst[h * HID + lane];
  #pragma unroll
  for (int off = 32; off; off >>= 1) {
    vs += __shfl_xor(vs, off);
    vd += __shfl_xor(vd, off);
  }
  if (lane == 0) { asrc[n * HEADS + h] = vs; adst[n * HEADS + h] = vd; }
}

__global__ __launch_bounds__(256) void alpha2_kernel(const float* __restrict__ H2,
                                                     const float* __restrict__ a_src,
                                                     const float* __restrict__ a_dst,
                                                     float* __restrict__ asrc,
                                                     float* __restrict__ adst, int N) {
  int g = blockIdx.x * 4 + (threadIdx.x >> 6);   // node id
  int lane = threadIdx.x & 63;
  if (g >= N) return;
  float hv = H2[(size_t)g * HID + lane];
  float vs = hv * a_src[lane];
  float vd = hv * a_dst[lane];
  #pragma unroll
  for (int off = 32; off; off >>= 1) {
    vs += __shfl_xor(vs, off);
    vd += __shfl_xor(vd, off);
  }
  if (lane == 0) { asrc[g] = vs; adst[g] = vd; }
}

// ---------------------------------------------------------------------------
// Edge softmax weights (no-max-subtraction: logits are O(4), exp is safe;
// softmax ratio is mathematically identical).  One thread per CSR entry.
// ---------------------------------------------------------------------------

__global__ __launch_bounds__(256) void edgew1_kernel(const int* __restrict__ srcs,
                                                     const int* __restrict__ edst,
                                                     const float* __restrict__ asrc,
                                                     const float* __restrict__ adst,
                                                     float* __restrict__ w,
                                                     float* __restrict__ ssum, int Etot) {
  int k = blockIdx.x * 256 + threadIdx.x;
  if (k >= Etot) return;
  int s = srcs[k], d = edst[k];
  float4 as = *(const float4*)&asrc[s * 4];
  float4 ad = *(const float4*)&adst[d * 4];
  float e0 = as.x + ad.x; e0 = (e0 > 0.f) ? e0 : 0.2f * e0;
  float e1 = as.y + ad.y; e1 = (e1 > 0.f) ? e1 : 0.2f * e1;
  float e2 = as.z + ad.z; e2 = (e2 > 0.f) ? e2 : 0.2f * e2;
  float e3 = as.w + ad.w; e3 = (e3 > 0.f) ? e3 : 0.2f * e3;
  float p0 = __expf(e0), p1 = __expf(e1), p2 = __expf(e2), p3 = __expf(e3);
  *(float4*)&w[k * 4] = make_float4(p0, p1, p2, p3);
  atomicAdd(&ssum[d * 4 + 0], p0);
  atomicAdd(&ssum[d * 4 + 1], p1);
  atomicAdd(&ssum[d * 4 + 2], p2);
  atomicAdd(&ssum[d * 4 + 3], p3);
}

__global__ __launch_bounds__(256) void edgew2_kernel(const int* __restrict__ srcs,
                                                     const int* __restrict__ edst,
                                                     const float* __restrict__ asrc,
                                                     const float* __restrict__ adst,
                                                     float* __restrict__ w,
                                                     float* __restrict__ ssum, int Etot) {
  int k = blockIdx.x * 256 + threadIdx.x;
  if (k >= Etot) return;
  int s = srcs[k], d = edst[k];
  float e = asrc[s] + adst[d];
  e = (e > 0.f) ? e : 0.2f * e;
  float p = __expf(e);
  w[k] = p;
  atomicAdd(&ssum[d], p);
}

// ---------------------------------------------------------------------------
// GAT aggregation (layer 1): one WAVE per dst node, lane = float4 of feats.
// Pure weighted gather + fused bias/BN/ELU epilogue.
// ---------------------------------------------------------------------------

__global__ __launch_bounds__(256) void gat1_agg(const float* __restrict__ H1,
                                                const float* __restrict__ w,
                                                const float* __restrict__ ssum,
                                                const int* __restrict__ indptr,
                                                const int* __restrict__ srcs,
                                                const float* __restrict__ b1,
                                                const float* __restrict__ g1,
                                                const float* __restrict__ be1,
                                                const float* __restrict__ mu1,
                                                const float* __restrict__ var1,
                                                float* __restrict__ X2, int N) {
  int n = blockIdx.x * 4 + (threadIdx.x >> 6);
  if (n >= N) return;
  int lane = threadIdx.x & 63;
  int h = lane >> 4;                 // head for this lane's 4 feats
  int f = lane * 4;
  int start = indptr[n], end = indptr[n + 1];

  float4 acc = make_float4(0.f, 0.f, 0.f, 0.f);
  int k = start;
  for (; k + 2 <= end; k += 2) {
    int s0 = srcs[k], s1 = srcs[k + 1];
    float w0 = w[k * 4 + h], w1v = w[(k + 1) * 4 + h];
    float4 r0 = *(const float4*)&H1[(size_t)s0 * C1 + f];
    float4 r1 = *(const float4*)&H1[(size_t)s1 * C1 + f];
    acc.x += w0 * r0.x + w1v * r1.x;
    acc.y += w0 * r0.y + w1v * r1.y;
    acc.z += w0 * r0.z + w1v * r1.z;
    acc.w += w0 * r0.w + w1v * r1.w;
  }
  if (k < end) {
    int s0 = srcs[k];
    float w0 = w[k * 4 + h];
    float4 r0 = *(const float4*)&H1[(size_t)s0 * C1 + f];
    acc.x += w0 * r0.x; acc.y += w0 * r0.y;
    acc.z += w0 * r0.z; acc.w += w0 * r0.w;
  }

  float inv = 1.f / (ssum[n * 4 + h] + 1e-16f);
  float4 bb = *(const float4*)&b1[f];
  float4 gg = *(const float4*)&g1[f];
  float4 ee = *(const float4*)&be1[f];
  float4 mm = *(const float4*)&mu1[f];
  float4 vv = *(const float4*)&var1[f];
  float4 val;
  val.x = (acc.x * inv + bb.x - mm.x) * (gg.x * rsqrtf(vv.x + 1e-5f)) + ee.x;
  val.y = (acc.y * inv + bb.y - mm.y) * (gg.y * rsqrtf(vv.y + 1e-5f)) + ee.y;
  val.z = (acc.z * inv + bb.z - mm.z) * (gg.z * rsqrtf(vv.z + 1e-5f)) + ee.z;
  val.w = (acc.w * inv + bb.w - mm.w) * (gg.w * rsqrtf(vv.w + 1e-5f)) + ee.w;
  val.x = (val.x > 0.f) ? val.x : (__expf(val.x) - 1.f);
  val.y = (val.y > 0.f) ? val.y : (__expf(val.y) - 1.f);
  val.z = (val.z > 0.f) ? val.z : (__expf(val.z) - 1.f);
  val.w = (val.w > 0.f) ? val.w : (__expf(val.w) - 1.f);
  *(float4*)&X2[(size_t)n * C1 + f] = val;
}

// ---------------------------------------------------------------------------
// GAT aggregation (layer 2): one wave per node, lane = feat (HID=64).
// ---------------------------------------------------------------------------

__global__ __launch_bounds__(256) void gat2_agg(const float* __restrict__ H2,
                                                const float* __restrict__ w,
                                                const float* __restrict__ ssum,
                                                const int* __restrict__ indptr,
                                                const int* __restrict__ srcs,
                                                const float* __restrict__ b2,
                                                const float* __restrict__ g2,
                                                const float* __restrict__ be2,
                                                const float* __restrict__ mu2,
                                                const float* __restrict__ var2,
                                                float* __restrict__ out, int N) {
  int n = blockIdx.x * 4 + (threadIdx.x >> 6);
  if (n >= N) return;
  int lane = threadIdx.x & 63;
  int start = indptr[n], end = indptr[n + 1];

  float acc = 0.f;
  int k = start;
  for (; k + 2 <= end; k += 2) {
    int s0 = srcs[k], s1 = srcs[k + 1];
    float w0 = w[k], w1v = w[k + 1];
    float r0 = H2[(size_t)s0 * HID + lane];
    float r1 = H2[(size_t)s1 * HID + lane];
    acc += w0 * r0 + w1v * r1;
  }
  if (k < end) {
    acc += w[k] * H2[(size_t)srcs[k] * HID + lane];
  }

  float val = acc / (ssum[n] + 1e-16f) + b2[lane];
  val = (val - mu2[lane]) * (g2[lane] * rsqrtf(var2[lane] + 1e-5f)) + be2[lane];
  val = (val > 0.f) ? val : (__expf(val) - 1.f);
  out[(size_t)n * HID + lane] = val;
}

// ---------------------------------------------------------------------------

extern "C" void kernel_launch(void* const* d_in, const int* in_sizes, int n_in,
                              void* d_out, int out_size, void* d_ws, size_t ws_size,
                              hipStream_t stream) {
  const float* x      = (const float*)d_in[0];
  const int*   ei     = (const int*)d_in[1];   // edge_index int32 [2,E]
  const float* W1     = (const float*)d_in[2];
  const float* a_src1 = (const float*)d_in[3];
  const float* a_dst1 = (const float*)d_in[4];
  const float* b1     = (const float*)d_in[5];
  const float* g1     = (const float*)d_in[6];
  const float* be1    = (const float*)d_in[7];
  const float* mu1    = (const float*)d_in[8];
  const float* var1   = (const float*)d_in[9];
  const float* W2     = (const float*)d_in[10];
  const float* a_src2 = (const float*)d_in[11];
  const float* a_dst2 = (const float*)d_in[12];
  const float* b2     = (const float*)d_in[13];
  const float* g2     = (const float*)d_in[14];
  const float* be2    = (const float*)d_in[15];
  const float* mu2    = (const float*)d_in[16];
  const float* var2   = (const float*)d_in[17];
  float* out = (float*)d_out;

  int N = in_sizes[0] / IN_DIM;
  int E = in_sizes[1] / 2;
  int Etot = E + N;

  // Workspace layout (~126 MB):
  //   H1 [N*C1] | X2 [N*C1] | asrc1 [4N] | adst1 [4N] |
  //   zblock { counts [N] | ssum1 [4N] | ssum2 [N] } |
  //   indptr [N+1] | fillpos [N] | srcs [Etot] | edst [Etot] | w1 [4*Etot]
  // Layer 2 reuses: H2 = H1 region; asrc2/adst2 beyond H2; w2 = w1 region.
  float* fws   = (float*)d_ws;
  float* H1    = fws;
  float* X2    = H1 + (size_t)N * C1;
  float* asrc1 = X2 + (size_t)N * C1;
  float* adst1 = asrc1 + (size_t)N * HEADS;
  int*   zbase = (int*)(adst1 + (size_t)N * HEADS);
  int*   counts = zbase;
  float* ssum1  = (float*)(zbase + N);
  float* ssum2  = ssum1 + (size_t)N * HEADS;
  int*   indptr  = (int*)(ssum2 + N);
  int*   fillpos = indptr + (N + 1);
  int*   srcs    = fillpos + N;
  int*   edst    = srcs + Etot;
  float* w1      = (float*)(edst + Etot);
  float* w2      = w1;                       // w1 dead before edgew2
  float* H2      = H1;                       // H1 dead after gat1_agg
  float* asrc2   = H1 + (size_t)N * HID;
  float* adst2   = asrc2 + N;

  // --- CSR build + zero accumulators ---
  zero_int_kernel<<<(6 * N + 255) / 256, 256, 0, stream>>>(zbase, 6 * N);
  hist_kernel<<<(Etot + 255) / 256, 256, 0, stream>>>(ei, E, N, counts);
  scan_kernel<<<1, 1024, 0, stream>>>(counts, indptr, fillpos, N);
  fill_kernel<<<(Etot + 255) / 256, 256, 0, stream>>>(ei, E, N, fillpos, srcs, edst);

  // --- Layer 1 ---
  gemm_kernel<<<dim3((N + 63) / 64, C1 / 64), 256, 0, stream>>>(x, W1, H1, N, C1, IN_DIM);
  alpha1_kernel<<<N, 256, 0, stream>>>(H1, a_src1, a_dst1, asrc1, adst1, N);
  edgew1_kernel<<<(Etot + 255) / 256, 256, 0, stream>>>(srcs, edst, asrc1, adst1, w1, ssum1, Etot);
  gat1_agg<<<(N + 3) / 4, 256, 0, stream>>>(H1, w1, ssum1, indptr, srcs,
                                            b1, g1, be1, mu1, var1, X2, N);

  // --- Layer 2 ---
  gemm_kernel<<<dim3((N + 63) / 64, HID / 64), 256, 0, stream>>>(X2, W2, H2, N, HID, C1);
  alpha2_kernel<<<(N + 3) / 4, 256, 0, stream>>>(H2, a_src2, a_dst2, asrc2, adst2, N);
  edgew2_kernel<<<(Etot + 255) / 256, 256, 0, stream>>>(srcs, edst, asrc2, adst2, w2, ssum2, Etot);
  gat2_agg<<<(N + 3) / 4, 256, 0, stream>>>(H2, w2, ssum2, indptr, srcs,
                                            b2, g2, be2, mu2, var2, out, N);
}

// Round 4
// 544.393 us; speedup vs baseline: 1.4508x; 1.4508x over previous
//
#include <hip/hip_runtime.h>

#define IN_DIM 256
#define HID 64
#define HEADS 4
#define C1 256   // HID*HEADS

// ---------------------------------------------------------------------------
// CSR build: histogram of dst -> exclusive scan -> atomic fill of (src,dst)
// ---------------------------------------------------------------------------

__global__ __launch_bounds__(256) void zero_int_kernel(int* __restrict__ p, int n) {
  int i = blockIdx.x * 256 + threadIdx.x;
  if (i < n) p[i] = 0;
}

__global__ __launch_bounds__(256) void hist_kernel(const int* __restrict__ ei,
                                                   int E, int N, int* __restrict__ counts) {
  int e = blockIdx.x * 256 + threadIdx.x;
  if (e >= E + N) return;
  int dst = (e < E) ? ei[(size_t)E + e] : (e - E);
  atomicAdd(&counts[dst], 1);
}

__global__ __launch_bounds__(1024) void scan_kernel(const int* __restrict__ counts,
                                                    int* __restrict__ indptr,
                                                    int* __restrict__ fillpos, int N) {
  __shared__ int sdata[1024];
  int tid = threadIdx.x;
  int running = 0;
  for (int base = 0; base < N; base += 1024) {
    int v = (base + tid < N) ? counts[base + tid] : 0;
    sdata[tid] = v;
    __syncthreads();
    for (int off = 1; off < 1024; off <<= 1) {
      int t = (tid >= off) ? sdata[tid - off] : 0;
      __syncthreads();
      sdata[tid] += t;
      __syncthreads();
    }
    int excl = sdata[tid] - v;
    if (base + tid < N) {
      indptr[base + tid] = running + excl;
      fillpos[base + tid] = running + excl;
    }
    int total = sdata[1023];
    __syncthreads();
    running += total;
  }
  if (tid == 0) indptr[N] = running;
}

__global__ __launch_bounds__(256) void fill_kernel(const int* __restrict__ ei, int E, int N,
                                                   int* __restrict__ fillpos,
                                                   int* __restrict__ srcs,
                                                   int* __restrict__ edst) {
  int e = blockIdx.x * 256 + threadIdx.x;
  if (e >= E + N) return;
  int src, dst;
  if (e < E) { src = ei[e]; dst = ei[(size_t)E + e]; }
  else       { src = e - E; dst = e - E; }
  int pos = atomicAdd(&fillpos[dst], 1);
  srcs[pos] = src;
  edst[pos] = dst;
}

// ---------------------------------------------------------------------------
// Tiled f32 GEMM: C[M,NC] = A[M,K] @ B[K,NC]   (BM=BN=64, BK=32, 4x4 micro)
// ---------------------------------------------------------------------------

__global__ __launch_bounds__(256) void gemm_kernel(const float* __restrict__ A,
                                                   const float* __restrict__ B,
                                                   float* __restrict__ C,
                                                   int M, int NC, int K) {
  const int BM = 64, BN = 64, BK = 32, TM = 4, TN = 4;
  __shared__ float As[BK][BM + 4];
  __shared__ float Bs[BK][BN + 4];
  int bm = blockIdx.x * BM;
  int bn = blockIdx.y * BN;
  int tid = threadIdx.x;
  int tr = tid >> 4;   // 0..15
  int tc = tid & 15;   // 0..15
  float acc[TM][TN] = {};
  for (int k0 = 0; k0 < K; k0 += BK) {
    #pragma unroll
    for (int it = 0; it < (BM * BK) / 256; ++it) {
      int i = tid + it * 256;
      int r = i >> 5, c = i & 31;
      int row = bm + r;
      As[c][r] = (row < M) ? A[(size_t)row * K + k0 + c] : 0.f;
    }
    #pragma unroll
    for (int it = 0; it < (BK * BN) / 256; ++it) {
      int i = tid + it * 256;
      int r = i >> 6, c = i & 63;
      Bs[r][c] = B[(size_t)(k0 + r) * NC + bn + c];
    }
    __syncthreads();
    #pragma unroll
    for (int k = 0; k < BK; ++k) {
      float a[TM], b[TN];
      #pragma unroll
      for (int i = 0; i < TM; ++i) a[i] = As[k][tr * TM + i];
      #pragma unroll
      for (int j = 0; j < TN; ++j) b[j] = Bs[k][tc * TN + j];
      #pragma unroll
      for (int i = 0; i < TM; ++i)
        #pragma unroll
        for (int j = 0; j < TN; ++j)
          acc[i][j] += a[i] * b[j];
    }
    __syncthreads();
  }
  #pragma unroll
  for (int i = 0; i < TM; ++i) {
    int row = bm + tr * TM + i;
    if (row < M) {
      #pragma unroll
      for (int j = 0; j < TN; ++j)
        C[(size_t)row * NC + bn + tc * TN + j] = acc[i][j];
    }
  }
}

// ---------------------------------------------------------------------------
// Attention logit projections
// ---------------------------------------------------------------------------

__global__ __launch_bounds__(256) void alpha1_kernel(const float* __restrict__ H1,
                                                     const float* __restrict__ a_src,
                                                     const float* __restrict__ a_dst,
                                                     float* __restrict__ asrc,
                                                     float* __restrict__ adst, int N) {
  int g = blockIdx.x * 4 + (threadIdx.x >> 6);   // group id over N*HEADS
  int lane = threadIdx.x & 63;
  int n = g >> 2, h = g & 3;
  if (n >= N) return;
  float hv = H1[(size_t)n * C1 + h * HID + lane];
  float vs = hv * a_src[h * HID + lane];
  float vd = hv * a_dst[h * HID + lane];
  #pragma unroll
  for (int off = 32; off; off >>= 1) {
    vs += __shfl_xor(vs, off);
    vd += __shfl_xor(vd, off);
  }
  if (lane == 0) { asrc[n * HEADS + h] = vs; adst[n * HEADS + h] = vd; }
}

__global__ __launch_bounds__(256) void alpha2_kernel(const float* __restrict__ H2,
                                                     const float* __restrict__ a_src,
                                                     const float* __restrict__ a_dst,
                                                     float* __restrict__ asrc,
                                                     float* __restrict__ adst, int N) {
  int g = blockIdx.x * 4 + (threadIdx.x >> 6);   // node id
  int lane = threadIdx.x & 63;
  if (g >= N) return;
  float hv = H2[(size_t)g * HID + lane];
  float vs = hv * a_src[lane];
  float vd = hv * a_dst[lane];
  #pragma unroll
  for (int off = 32; off; off >>= 1) {
    vs += __shfl_xor(vs, off);
    vd += __shfl_xor(vd, off);
  }
  if (lane == 0) { asrc[g] = vs; adst[g] = vd; }
}

// ---------------------------------------------------------------------------
// Edge softmax weights — pure streaming, NO atomics (denominator is summed
// inline in the aggregation kernels).  No-max-subtraction: logits are O(4),
// exp is safe; softmax ratio is mathematically identical.
// ---------------------------------------------------------------------------

__global__ __launch_bounds__(256) void edgew1_kernel(const int* __restrict__ srcs,
                                                     const int* __restrict__ edst,
                                                     const float* __restrict__ asrc,
                                                     const float* __restrict__ adst,
                                                     float* __restrict__ w, int Etot) {
  int k = blockIdx.x * 256 + threadIdx.x;
  if (k >= Etot) return;
  int s = srcs[k], d = edst[k];
  float4 as = *(const float4*)&asrc[s * 4];
  float4 ad = *(const float4*)&adst[d * 4];
  float e0 = as.x + ad.x; e0 = (e0 > 0.f) ? e0 : 0.2f * e0;
  float e1 = as.y + ad.y; e1 = (e1 > 0.f) ? e1 : 0.2f * e1;
  float e2 = as.z + ad.z; e2 = (e2 > 0.f) ? e2 : 0.2f * e2;
  float e3 = as.w + ad.w; e3 = (e3 > 0.f) ? e3 : 0.2f * e3;
  *(float4*)&w[k * 4] = make_float4(__expf(e0), __expf(e1), __expf(e2), __expf(e3));
}

__global__ __launch_bounds__(256) void edgew2_kernel(const int* __restrict__ srcs,
                                                     const int* __restrict__ edst,
                                                     const float* __restrict__ asrc,
                                                     const float* __restrict__ adst,
                                                     float* __restrict__ w, int Etot) {
  int k = blockIdx.x * 256 + threadIdx.x;
  if (k >= Etot) return;
  float e = asrc[srcs[k]] + adst[edst[k]];
  e = (e > 0.f) ? e : 0.2f * e;
  w[k] = __expf(e);
}

// ---------------------------------------------------------------------------
// GAT aggregation (layer 1): one WAVE per dst node, lane = float4 of feats.
// Weighted gather; denominator summed inline; fused bias/BN/ELU epilogue.
// ---------------------------------------------------------------------------

__global__ __launch_bounds__(256) void gat1_agg(const float* __restrict__ H1,
                                                const float* __restrict__ w,
                                                const int* __restrict__ indptr,
                                                const int* __restrict__ srcs,
                                                const float* __restrict__ b1,
                                                const float* __restrict__ g1,
                                                const float* __restrict__ be1,
                                                const float* __restrict__ mu1,
                                                const float* __restrict__ var1,
                                                float* __restrict__ X2, int N) {
  int n = blockIdx.x * 4 + (threadIdx.x >> 6);
  if (n >= N) return;
  int lane = threadIdx.x & 63;
  int h = lane >> 4;                 // head for this lane's 4 feats
  int f = lane * 4;
  int start = indptr[n], end = indptr[n + 1];

  float4 acc = make_float4(0.f, 0.f, 0.f, 0.f);
  float wsum = 0.f;
  int k = start;
  for (; k + 2 <= end; k += 2) {
    int s0 = srcs[k], s1 = srcs[k + 1];
    float w0 = w[k * 4 + h], w1v = w[(k + 1) * 4 + h];
    float4 r0 = *(const float4*)&H1[(size_t)s0 * C1 + f];
    float4 r1 = *(const float4*)&H1[(size_t)s1 * C1 + f];
    wsum += w0 + w1v;
    acc.x += w0 * r0.x + w1v * r1.x;
    acc.y += w0 * r0.y + w1v * r1.y;
    acc.z += w0 * r0.z + w1v * r1.z;
    acc.w += w0 * r0.w + w1v * r1.w;
  }
  if (k < end) {
    int s0 = srcs[k];
    float w0 = w[k * 4 + h];
    float4 r0 = *(const float4*)&H1[(size_t)s0 * C1 + f];
    wsum += w0;
    acc.x += w0 * r0.x; acc.y += w0 * r0.y;
    acc.z += w0 * r0.z; acc.w += w0 * r0.w;
  }

  float inv = 1.f / (wsum + 1e-16f);
  float4 bb = *(const float4*)&b1[f];
  float4 gg = *(const float4*)&g1[f];
  float4 ee = *(const float4*)&be1[f];
  float4 mm = *(const float4*)&mu1[f];
  float4 vv = *(const float4*)&var1[f];
  float4 val;
  val.x = (acc.x * inv + bb.x - mm.x) * (gg.x * rsqrtf(vv.x + 1e-5f)) + ee.x;
  val.y = (acc.y * inv + bb.y - mm.y) * (gg.y * rsqrtf(vv.y + 1e-5f)) + ee.y;
  val.z = (acc.z * inv + bb.z - mm.z) * (gg.z * rsqrtf(vv.z + 1e-5f)) + ee.z;
  val.w = (acc.w * inv + bb.w - mm.w) * (gg.w * rsqrtf(vv.w + 1e-5f)) + ee.w;
  val.x = (val.x > 0.f) ? val.x : (__expf(val.x) - 1.f);
  val.y = (val.y > 0.f) ? val.y : (__expf(val.y) - 1.f);
  val.z = (val.z > 0.f) ? val.z : (__expf(val.z) - 1.f);
  val.w = (val.w > 0.f) ? val.w : (__expf(val.w) - 1.f);
  *(float4*)&X2[(size_t)n * C1 + f] = val;
}

// ---------------------------------------------------------------------------
// GAT aggregation (layer 2): one wave per node, lane = feat (HID=64).
// ---------------------------------------------------------------------------

__global__ __launch_bounds__(256) void gat2_agg(const float* __restrict__ H2,
                                                const float* __restrict__ w,
                                                const int* __restrict__ indptr,
                                                const int* __restrict__ srcs,
                                                const float* __restrict__ b2,
                                                const float* __restrict__ g2,
                                                const float* __restrict__ be2,
                                                const float* __restrict__ mu2,
                                                const float* __restrict__ var2,
                                                float* __restrict__ out, int N) {
  int n = blockIdx.x * 4 + (threadIdx.x >> 6);
  if (n >= N) return;
  int lane = threadIdx.x & 63;
  int start = indptr[n], end = indptr[n + 1];

  float acc = 0.f, wsum = 0.f;
  int k = start;
  for (; k + 2 <= end; k += 2) {
    int s0 = srcs[k], s1 = srcs[k + 1];
    float w0 = w[k], w1v = w[k + 1];
    float r0 = H2[(size_t)s0 * HID + lane];
    float r1 = H2[(size_t)s1 * HID + lane];
    wsum += w0 + w1v;
    acc += w0 * r0 + w1v * r1;
  }
  if (k < end) {
    float w0 = w[k];
    wsum += w0;
    acc += w0 * H2[(size_t)srcs[k] * HID + lane];
  }

  float val = acc / (wsum + 1e-16f) + b2[lane];
  val = (val - mu2[lane]) * (g2[lane] * rsqrtf(var2[lane] + 1e-5f)) + be2[lane];
  val = (val > 0.f) ? val : (__expf(val) - 1.f);
  out[(size_t)n * HID + lane] = val;
}

// ---------------------------------------------------------------------------

extern "C" void kernel_launch(void* const* d_in, const int* in_sizes, int n_in,
                              void* d_out, int out_size, void* d_ws, size_t ws_size,
                              hipStream_t stream) {
  const float* x      = (const float*)d_in[0];
  const int*   ei     = (const int*)d_in[1];   // edge_index int32 [2,E]
  const float* W1     = (const float*)d_in[2];
  const float* a_src1 = (const float*)d_in[3];
  const float* a_dst1 = (const float*)d_in[4];
  const float* b1     = (const float*)d_in[5];
  const float* g1     = (const float*)d_in[6];
  const float* be1    = (const float*)d_in[7];
  const float* mu1    = (const float*)d_in[8];
  const float* var1   = (const float*)d_in[9];
  const float* W2     = (const float*)d_in[10];
  const float* a_src2 = (const float*)d_in[11];
  const float* a_dst2 = (const float*)d_in[12];
  const float* b2     = (const float*)d_in[13];
  const float* g2     = (const float*)d_in[14];
  const float* be2    = (const float*)d_in[15];
  const float* mu2    = (const float*)d_in[16];
  const float* var2   = (const float*)d_in[17];
  float* out = (float*)d_out;

  int N = in_sizes[0] / IN_DIM;
  int E = in_sizes[1] / 2;
  int Etot = E + N;

  // Workspace layout (~125 MB):
  //   H1 [N*C1] | X2 [N*C1] | asrc1 [4N] | adst1 [4N] |
  //   counts [N] | indptr [N+1] | fillpos [N] | srcs [Etot] | edst [Etot] |
  //   w1 [4*Etot]
  // Layer 2 reuses: H2 = H1 region; asrc2/adst2 beyond H2; w2 = w1 region.
  float* fws   = (float*)d_ws;
  float* H1    = fws;
  float* X2    = H1 + (size_t)N * C1;
  float* asrc1 = X2 + (size_t)N * C1;
  float* adst1 = asrc1 + (size_t)N * HEADS;
  int*   counts  = (int*)(adst1 + (size_t)N * HEADS);
  int*   indptr  = counts + N;
  int*   fillpos = indptr + (N + 1);
  int*   srcs    = fillpos + N;
  int*   edst    = srcs + Etot;
  float* w1      = (float*)(edst + Etot);
  float* w2      = w1;                       // w1 dead before edgew2
  float* H2      = H1;                       // H1 dead after gat1_agg
  float* asrc2   = H1 + (size_t)N * HID;
  float* adst2   = asrc2 + N;

  // --- CSR build ---
  zero_int_kernel<<<(N + 255) / 256, 256, 0, stream>>>(counts, N);
  hist_kernel<<<(Etot + 255) / 256, 256, 0, stream>>>(ei, E, N, counts);
  scan_kernel<<<1, 1024, 0, stream>>>(counts, indptr, fillpos, N);
  fill_kernel<<<(Etot + 255) / 256, 256, 0, stream>>>(ei, E, N, fillpos, srcs, edst);

  // --- Layer 1 ---
  gemm_kernel<<<dim3((N + 63) / 64, C1 / 64), 256, 0, stream>>>(x, W1, H1, N, C1, IN_DIM);
  alpha1_kernel<<<N, 256, 0, stream>>>(H1, a_src1, a_dst1, asrc1, adst1, N);
  edgew1_kernel<<<(Etot + 255) / 256, 256, 0, stream>>>(srcs, edst, asrc1, adst1, w1, Etot);
  gat1_agg<<<(N + 3) / 4, 256, 0, stream>>>(H1, w1, indptr, srcs,
                                            b1, g1, be1, mu1, var1, X2, N);

  // --- Layer 2 ---
  gemm_kernel<<<dim3((N + 63) / 64, HID / 64), 256, 0, stream>>>(X2, W2, H2, N, HID, C1);
  alpha2_kernel<<<(N + 3) / 4, 256, 0, stream>>>(H2, a_src2, a_dst2, asrc2, adst2, N);
  edgew2_kernel<<<(Etot + 255) / 256, 256, 0, stream>>>(srcs, edst, asrc2, adst2, w2, Etot);
  gat2_agg<<<(N + 3) / 4, 256, 0, stream>>>(H2, w2, indptr, srcs,
                                            b2, g2, be2, mu2, var2, out, N);
}

// Round 5
// 387.034 us; speedup vs baseline: 2.0406x; 1.4066x over previous
//
#include <hip/hip_runtime.h>

#define IN_DIM 256
#define HID 64
#define HEADS 4
#define C1 256   // HID*HEADS

typedef __attribute__((ext_vector_type(4))) float  f32x4;
typedef __attribute__((ext_vector_type(8))) short  short8;
typedef __attribute__((ext_vector_type(8))) unsigned short ushort8;
typedef __attribute__((ext_vector_type(4))) unsigned short ushort4v;

static __device__ __forceinline__ unsigned short f2bf(float f) {
  union { float f; unsigned int u; } v; v.f = f;
  unsigned int r = v.u + 0x7fffu + ((v.u >> 16) & 1u);   // RNE
  return (unsigned short)(r >> 16);
}
static __device__ __forceinline__ float bf2f(unsigned short u) {
  union { unsigned int u; float f; } v; v.u = ((unsigned int)u) << 16;
  return v.f;
}

// ---------------------------------------------------------------------------
// CSR build
// ---------------------------------------------------------------------------

__global__ __launch_bounds__(256) void zero_int_kernel(int* __restrict__ p, int n) {
  int i = blockIdx.x * 256 + threadIdx.x;
  if (i < n) p[i] = 0;
}

__global__ __launch_bounds__(256) void hist_kernel(const int* __restrict__ ei,
                                                   int E, int N, int* __restrict__ counts) {
  int e = blockIdx.x * 256 + threadIdx.x;
  if (e >= E + N) return;
  int dst = (e < E) ? ei[(size_t)E + e] : (e - E);
  atomicAdd(&counts[dst], 1);
}

// chunked scan: per-thread serial sum -> one block scan -> serial prefix write
__global__ __launch_bounds__(1024) void scan_kernel(const int* __restrict__ counts,
                                                    int* __restrict__ indptr,
                                                    int* __restrict__ fillpos, int N) {
  __shared__ int sums[1024];
  int tid = threadIdx.x;
  int CH = (N + 1023) / 1024;
  int beg = tid * CH;
  int end = min(beg + CH, N);
  int s = 0;
  for (int i = beg; i < end; ++i) s += counts[i];
  sums[tid] = s;
  __syncthreads();
  for (int off = 1; off < 1024; off <<= 1) {
    int t = (tid >= off) ? sums[tid - off] : 0;
    __syncthreads();
    sums[tid] += t;
    __syncthreads();
  }
  int p = sums[tid] - s;   // exclusive prefix of this chunk
  for (int i = beg; i < end; ++i) {
    indptr[i] = p; fillpos[i] = p;
    p += counts[i];
  }
  if (end == N) indptr[N] = p;   // all qualifying threads write the same total
}

__global__ __launch_bounds__(256) void fill_kernel(const int* __restrict__ ei, int E, int N,
                                                   int* __restrict__ fillpos,
                                                   int* __restrict__ srcs,
                                                   int* __restrict__ edst) {
  int e = blockIdx.x * 256 + threadIdx.x;
  if (e >= E + N) return;
  int src, dst;
  if (e < E) { src = ei[e]; dst = ei[(size_t)E + e]; }
  else       { src = e - E; dst = e - E; }
  int pos = atomicAdd(&fillpos[dst], 1);
  srcs[pos] = src;
  edst[pos] = dst;
}

// ---------------------------------------------------------------------------
// Conversions: x -> bf16; W -> bf16 transposed ([n][k]) so GEMM A and B tiles
// share the identical [row][k] LDS pattern.
// ---------------------------------------------------------------------------

__global__ __launch_bounds__(256) void convx_kernel(const float* __restrict__ in,
                                                    unsigned short* __restrict__ outb, int n8) {
  int i = blockIdx.x * 256 + threadIdx.x;
  if (i >= n8) return;
  const float4* p = (const float4*)(in + (size_t)i * 8);
  float4 a = p[0], b = p[1];
  ushort8 o;
  o[0]=f2bf(a.x); o[1]=f2bf(a.y); o[2]=f2bf(a.z); o[3]=f2bf(a.w);
  o[4]=f2bf(b.x); o[5]=f2bf(b.y); o[6]=f2bf(b.z); o[7]=f2bf(b.w);
  *(ushort8*)(outb + (size_t)i * 8) = o;
}

// W[k][n] (f32, KxNC) -> Wt[n][k] (bf16, NCxK)
__global__ __launch_bounds__(256) void convwt_kernel(const float* __restrict__ W,
                                                     unsigned short* __restrict__ Wt,
                                                     int K, int NC) {
  int t = blockIdx.x * 256 + threadIdx.x;
  if (t >= K * NC) return;
  int k = t & (K - 1);      // K is 256 (pow2)
  int n = t >> 8;
  Wt[(size_t)n * K + k] = f2bf(W[(size_t)k * NC + n]);
}

// ---------------------------------------------------------------------------
// bf16 MFMA GEMM: C[M,NC](bf16) = A[M,K](bf16) @ Bt[NC,K](bf16, pre-transposed)
// BM=BN=64, BK=32; 4 waves, each 32x32 (2x2 frags of 16x16x32).
// ---------------------------------------------------------------------------

#define LDT 40   // padded LDS row stride (elements); 80B = 5*16B, aligned

__global__ __launch_bounds__(256) void gemm_bf16_kernel(const unsigned short* __restrict__ A,
                                                        const unsigned short* __restrict__ Bt,
                                                        unsigned short* __restrict__ C,
                                                        int M, int NC, int K) {
  __shared__ unsigned short As[64 * LDT];
  __shared__ unsigned short Bs[64 * LDT];
  int bm = blockIdx.x * 64, bn = blockIdx.y * 64;
  int tid = threadIdx.x;
  int wid = tid >> 6, lane = tid & 63;
  int wr = (wid >> 1) * 32, wc = (wid & 1) * 32;
  int lrow = tid >> 2;            // 0..63
  int lk   = (tid & 3) * 8;       // 0,8,16,24

  f32x4 acc00 = {0,0,0,0}, acc01 = {0,0,0,0}, acc10 = {0,0,0,0}, acc11 = {0,0,0,0};
  int l15 = lane & 15, lq = lane >> 4;

  for (int k0 = 0; k0 < K; k0 += 32) {
    int arow = bm + lrow;
    ushort8 av = {0,0,0,0,0,0,0,0};
    if (arow < M) av = *(const ushort8*)&A[(size_t)arow * K + k0 + lk];
    *(ushort8*)&As[lrow * LDT + lk] = av;
    ushort8 bv = *(const ushort8*)&Bt[(size_t)(bn + lrow) * K + k0 + lk];
    *(ushort8*)&Bs[lrow * LDT + lk] = bv;
    __syncthreads();

    short8 a0 = *(const short8*)&As[(wr + l15) * LDT + lq * 8];
    short8 a1 = *(const short8*)&As[(wr + 16 + l15) * LDT + lq * 8];
    short8 b0 = *(const short8*)&Bs[(wc + l15) * LDT + lq * 8];
    short8 b1 = *(const short8*)&Bs[(wc + 16 + l15) * LDT + lq * 8];
    acc00 = __builtin_amdgcn_mfma_f32_16x16x32_bf16(a0, b0, acc00, 0, 0, 0);
    acc01 = __builtin_amdgcn_mfma_f32_16x16x32_bf16(a0, b1, acc01, 0, 0, 0);
    acc10 = __builtin_amdgcn_mfma_f32_16x16x32_bf16(a1, b0, acc10, 0, 0, 0);
    acc11 = __builtin_amdgcn_mfma_f32_16x16x32_bf16(a1, b1, acc11, 0, 0, 0);
    __syncthreads();
  }

  // C/D layout (verified): col = lane&15, row = (lane>>4)*4 + reg
  #pragma unroll
  for (int r = 0; r < 4; ++r) {
    int row0 = bm + wr + lq * 4 + r;
    int row1 = row0 + 16;
    int colb = bn + wc + l15;
    if (row0 < M) {
      C[(size_t)row0 * NC + colb]      = f2bf(acc00[r]);
      C[(size_t)row0 * NC + colb + 16] = f2bf(acc01[r]);
    }
    if (row1 < M) {
      C[(size_t)row1 * NC + colb]      = f2bf(acc10[r]);
      C[(size_t)row1 * NC + colb + 16] = f2bf(acc11[r]);
    }
  }
}

// ---------------------------------------------------------------------------
// Attention logit projections (bf16 H)
// ---------------------------------------------------------------------------

// wave per node; lane covers feats 4l..4l+3 (256 feats)
__global__ __launch_bounds__(256) void alpha1_kernel(const unsigned short* __restrict__ H1b,
                                                     const float* __restrict__ a_src,
                                                     const float* __restrict__ a_dst,
                                                     float* __restrict__ asrc,
                                                     float* __restrict__ adst, int N) {
  int n = blockIdx.x * 4 + (threadIdx.x >> 6);
  if (n >= N) return;
  int lane = threadIdx.x & 63;
  int h = lane >> 4;
  ushort4v raw = *(const ushort4v*)&H1b[(size_t)n * C1 + lane * 4];
  float4 as = *(const float4*)&a_src[h * HID + (lane & 15) * 4];
  float4 ad = *(const float4*)&a_dst[h * HID + (lane & 15) * 4];
  float h0 = bf2f(raw[0]), h1 = bf2f(raw[1]), h2 = bf2f(raw[2]), h3 = bf2f(raw[3]);
  float vs = h0 * as.x + h1 * as.y + h2 * as.z + h3 * as.w;
  float vd = h0 * ad.x + h1 * ad.y + h2 * ad.z + h3 * ad.w;
  #pragma unroll
  for (int off = 1; off < 16; off <<= 1) {
    vs += __shfl_xor(vs, off);
    vd += __shfl_xor(vd, off);
  }
  if ((lane & 15) == 0) {
    asrc[n * HEADS + h] = vs;
    adst[n * HEADS + h] = vd;
  }
}

// wave per node; lanes use l&31 (duplicated halves), feats 2j..2j+1
__global__ __launch_bounds__(256) void alpha2_kernel(const unsigned short* __restrict__ H2b,
                                                     const float* __restrict__ a_src,
                                                     const float* __restrict__ a_dst,
                                                     float* __restrict__ asrc,
                                                     float* __restrict__ adst, int N) {
  int n = blockIdx.x * 4 + (threadIdx.x >> 6);
  if (n >= N) return;
  int lane = threadIdx.x & 63;
  int j = lane & 31;
  unsigned int raw = *(const unsigned int*)&H2b[(size_t)n * HID + j * 2];
  float h0 = bf2f((unsigned short)(raw & 0xffff));
  float h1 = bf2f((unsigned short)(raw >> 16));
  float vs = h0 * a_src[j * 2] + h1 * a_src[j * 2 + 1];
  float vd = h0 * a_dst[j * 2] + h1 * a_dst[j * 2 + 1];
  #pragma unroll
  for (int off = 1; off < 32; off <<= 1) {
    vs += __shfl_xor(vs, off);
    vd += __shfl_xor(vd, off);
  }
  if (lane == 0) { asrc[n] = vs; adst[n] = vd; }
}

// ---------------------------------------------------------------------------
// Edge softmax weights — streaming, no atomics
// ---------------------------------------------------------------------------

__global__ __launch_bounds__(256) void edgew1_kernel(const int* __restrict__ srcs,
                                                     const int* __restrict__ edst,
                                                     const float* __restrict__ asrc,
                                                     const float* __restrict__ adst,
                                                     float* __restrict__ w, int Etot) {
  int k = blockIdx.x * 256 + threadIdx.x;
  if (k >= Etot) return;
  int s = srcs[k], d = edst[k];
  float4 as = *(const float4*)&asrc[s * 4];
  float4 ad = *(const float4*)&adst[d * 4];
  float e0 = as.x + ad.x; e0 = (e0 > 0.f) ? e0 : 0.2f * e0;
  float e1 = as.y + ad.y; e1 = (e1 > 0.f) ? e1 : 0.2f * e1;
  float e2 = as.z + ad.z; e2 = (e2 > 0.f) ? e2 : 0.2f * e2;
  float e3 = as.w + ad.w; e3 = (e3 > 0.f) ? e3 : 0.2f * e3;
  *(float4*)&w[k * 4] = make_float4(__expf(e0), __expf(e1), __expf(e2), __expf(e3));
}

__global__ __launch_bounds__(256) void edgew2_kernel(const int* __restrict__ srcs,
                                                     const int* __restrict__ edst,
                                                     const float* __restrict__ asrc,
                                                     const float* __restrict__ adst,
                                                     float* __restrict__ w, int Etot) {
  int k = blockIdx.x * 256 + threadIdx.x;
  if (k >= Etot) return;
  float e = asrc[srcs[k]] + adst[edst[k]];
  e = (e > 0.f) ? e : 0.2f * e;
  w[k] = __expf(e);
}

// ---------------------------------------------------------------------------
// GAT agg layer 1 (bf16 H1): wave per node, split-wave 2 edges/iter.
// lane = (half = l>>5, j = l&31); lane covers feats 8j..8j+7 (16B read).
// ---------------------------------------------------------------------------

__global__ __launch_bounds__(256) void gat1_agg(const unsigned short* __restrict__ H1b,
                                                const float* __restrict__ w,
                                                const int* __restrict__ indptr,
                                                const int* __restrict__ srcs,
                                                const float* __restrict__ b1,
                                                const float* __restrict__ g1,
                                                const float* __restrict__ be1,
                                                const float* __restrict__ mu1,
                                                const float* __restrict__ var1,
                                                unsigned short* __restrict__ X2b, int N) {
  int n = blockIdx.x * 4 + (threadIdx.x >> 6);
  if (n >= N) return;
  int lane = threadIdx.x & 63;
  int half = lane >> 5;
  int j = lane & 31;
  int h = j >> 3;
  int start = indptr[n], end = indptr[n + 1];

  float acc[8] = {0.f,0.f,0.f,0.f,0.f,0.f,0.f,0.f};
  float wsum = 0.f;
  for (int k = start + half; k < end; k += 2) {
    int s = srcs[k];
    float wt = w[k * 4 + h];
    ushort8 raw = *(const ushort8*)&H1b[(size_t)s * C1 + j * 8];
    wsum += wt;
    #pragma unroll
    for (int i = 0; i < 8; ++i) acc[i] += wt * bf2f(raw[i]);
  }
  #pragma unroll
  for (int i = 0; i < 8; ++i) acc[i] += __shfl_xor(acc[i], 32);
  wsum += __shfl_xor(wsum, 32);

  if (half == 0) {
    float inv = 1.f / (wsum + 1e-16f);
    int f = j * 8;
    float4 bb0 = *(const float4*)&b1[f],   bb1 = *(const float4*)&b1[f + 4];
    float4 gg0 = *(const float4*)&g1[f],   gg1 = *(const float4*)&g1[f + 4];
    float4 ee0 = *(const float4*)&be1[f],  ee1 = *(const float4*)&be1[f + 4];
    float4 mm0 = *(const float4*)&mu1[f],  mm1 = *(const float4*)&mu1[f + 4];
    float4 vv0 = *(const float4*)&var1[f], vv1 = *(const float4*)&var1[f + 4];
    float bbv[8] = {bb0.x,bb0.y,bb0.z,bb0.w, bb1.x,bb1.y,bb1.z,bb1.w};
    float ggv[8] = {gg0.x,gg0.y,gg0.z,gg0.w, gg1.x,gg1.y,gg1.z,gg1.w};
    float eev[8] = {ee0.x,ee0.y,ee0.z,ee0.w, ee1.x,ee1.y,ee1.z,ee1.w};
    float mmv[8] = {mm0.x,mm0.y,mm0.z,mm0.w, mm1.x,mm1.y,mm1.z,mm1.w};
    float vvv[8] = {vv0.x,vv0.y,vv0.z,vv0.w, vv1.x,vv1.y,vv1.z,vv1.w};
    ushort8 o;
    #pragma unroll
    for (int i = 0; i < 8; ++i) {
      float val = (acc[i] * inv + bbv[i] - mmv[i]) * (ggv[i] * rsqrtf(vvv[i] + 1e-5f)) + eev[i];
      val = (val > 0.f) ? val : (__expf(val) - 1.f);
      o[i] = f2bf(val);
    }
    *(ushort8*)&X2b[(size_t)n * C1 + f] = o;
  }
}

// ---------------------------------------------------------------------------
// GAT agg layer 2 (bf16 H2): wave per node, quarter-wave 4 edges/iter.
// lane = (q = l>>4, j = l&15); lane covers feats 4j..4j+3 (8B read). f32 out.
// ---------------------------------------------------------------------------

__global__ __launch_bounds__(256) void gat2_agg(const unsigned short* __restrict__ H2b,
                                                const float* __restrict__ w,
                                                const int* __restrict__ indptr,
                                                const int* __restrict__ srcs,
                                                const float* __restrict__ b2,
                                                const float* __restrict__ g2,
                                                const float* __restrict__ be2,
                                                const float* __restrict__ mu2,
                                                const float* __restrict__ var2,
                                                float* __restrict__ out, int N) {
  int n = blockIdx.x * 4 + (threadIdx.x >> 6);
  if (n >= N) return;
  int lane = threadIdx.x & 63;
  int q = lane >> 4;
  int j = lane & 15;
  int start = indptr[n], end = indptr[n + 1];

  float acc[4] = {0.f,0.f,0.f,0.f};
  float wsum = 0.f;
  for (int k = start + q; k < end; k += 4) {
    int s = srcs[k];
    float wt = w[k];
    ushort4v raw = *(const ushort4v*)&H2b[(size_t)s * HID + j * 4];
    wsum += wt;
    #pragma unroll
    for (int i = 0; i < 4; ++i) acc[i] += wt * bf2f(raw[i]);
  }
  #pragma unroll
  for (int i = 0; i < 4; ++i) {
    acc[i] += __shfl_xor(acc[i], 16);
    acc[i] += __shfl_xor(acc[i], 32);
  }
  wsum += __shfl_xor(wsum, 16);
  wsum += __shfl_xor(wsum, 32);

  if (q == 0) {
    float inv = 1.f / (wsum + 1e-16f);
    int f = j * 4;
    float4 bb = *(const float4*)&b2[f];
    float4 gg = *(const float4*)&g2[f];
    float4 ee = *(const float4*)&be2[f];
    float4 mm = *(const float4*)&mu2[f];
    float4 vv = *(const float4*)&var2[f];
    float4 val;
    val.x = (acc[0] * inv + bb.x - mm.x) * (gg.x * rsqrtf(vv.x + 1e-5f)) + ee.x;
    val.y = (acc[1] * inv + bb.y - mm.y) * (gg.y * rsqrtf(vv.y + 1e-5f)) + ee.y;
    val.z = (acc[2] * inv + bb.z - mm.z) * (gg.z * rsqrtf(vv.z + 1e-5f)) + ee.z;
    val.w = (acc[3] * inv + bb.w - mm.w) * (gg.w * rsqrtf(vv.w + 1e-5f)) + ee.w;
    val.x = (val.x > 0.f) ? val.x : (__expf(val.x) - 1.f);
    val.y = (val.y > 0.f) ? val.y : (__expf(val.y) - 1.f);
    val.z = (val.z > 0.f) ? val.z : (__expf(val.z) - 1.f);
    val.w = (val.w > 0.f) ? val.w : (__expf(val.w) - 1.f);
    *(float4*)&out[(size_t)n * HID + f] = val;
  }
}

// ---------------------------------------------------------------------------

extern "C" void kernel_launch(void* const* d_in, const int* in_sizes, int n_in,
                              void* d_out, int out_size, void* d_ws, size_t ws_size,
                              hipStream_t stream) {
  const float* x      = (const float*)d_in[0];
  const int*   ei     = (const int*)d_in[1];
  const float* W1     = (const float*)d_in[2];
  const float* a_src1 = (const float*)d_in[3];
  const float* a_dst1 = (const float*)d_in[4];
  const float* b1     = (const float*)d_in[5];
  const float* g1     = (const float*)d_in[6];
  const float* be1    = (const float*)d_in[7];
  const float* mu1    = (const float*)d_in[8];
  const float* var1   = (const float*)d_in[9];
  const float* W2     = (const float*)d_in[10];
  const float* a_src2 = (const float*)d_in[11];
  const float* a_dst2 = (const float*)d_in[12];
  const float* b2     = (const float*)d_in[13];
  const float* g2     = (const float*)d_in[14];
  const float* be2    = (const float*)d_in[15];
  const float* mu2    = (const float*)d_in[16];
  const float* var2   = (const float*)d_in[17];
  float* out = (float*)d_out;

  int N = in_sizes[0] / IN_DIM;
  int E = in_sizes[1] / 2;
  int Etot = E + N;

  // Workspace (~100 MB). 16B-aligned region first (all sizes multiple of 16B):
  //   xb[N*256]b | H1b[N*256]b (reused as H2b) | X2b[N*256]b | W1t[256*256]b |
  //   W2t[64*256]b | w1[4*Etot]f (reused as w2) | asrc1[4N]f | adst1[4N]f |
  //   asrc2[N]f | adst2[N]f | counts[N] | indptr[N+1] | fillpos[N] |
  //   srcs[Etot] | edst[Etot]
  unsigned short* xb  = (unsigned short*)d_ws;
  unsigned short* H1b = xb  + (size_t)N * C1;
  unsigned short* X2b = H1b + (size_t)N * C1;
  unsigned short* W1t = X2b + (size_t)N * C1;
  unsigned short* W2t = W1t + 256 * 256;
  float* w1    = (float*)(W2t + 64 * 256);
  float* asrc1 = w1 + (size_t)4 * Etot;
  float* adst1 = asrc1 + (size_t)N * HEADS;
  float* asrc2 = adst1 + (size_t)N * HEADS;
  float* adst2 = asrc2 + N;
  int* counts  = (int*)(adst2 + N);
  int* indptr  = counts + N;
  int* fillpos = indptr + (N + 1);
  int* srcs    = fillpos + N;
  int* edst    = srcs + Etot;
  unsigned short* H2b = H1b;   // H1b dead after gat1_agg
  float* w2 = w1;              // w1 dead before edgew2

  // --- CSR build ---
  zero_int_kernel<<<(N + 255) / 256, 256, 0, stream>>>(counts, N);
  hist_kernel<<<(Etot + 255) / 256, 256, 0, stream>>>(ei, E, N, counts);
  scan_kernel<<<1, 1024, 0, stream>>>(counts, indptr, fillpos, N);
  fill_kernel<<<(Etot + 255) / 256, 256, 0, stream>>>(ei, E, N, fillpos, srcs, edst);

  // --- Conversions ---
  int n8 = N * C1 / 8;
  convx_kernel<<<(n8 + 255) / 256, 256, 0, stream>>>(x, xb, n8);
  convwt_kernel<<<(256 * 256 + 255) / 256, 256, 0, stream>>>(W1, W1t, 256, C1);
  convwt_kernel<<<(256 * 64 + 255) / 256, 256, 0, stream>>>(W2, W2t, 256, HID);

  // --- Layer 1 ---
  gemm_bf16_kernel<<<dim3((N + 63) / 64, C1 / 64), 256, 0, stream>>>(xb, W1t, H1b, N, C1, IN_DIM);
  alpha1_kernel<<<(N + 3) / 4, 256, 0, stream>>>(H1b, a_src1, a_dst1, asrc1, adst1, N);
  edgew1_kernel<<<(Etot + 255) / 256, 256, 0, stream>>>(srcs, edst, asrc1, adst1, w1, Etot);
  gat1_agg<<<(N + 3) / 4, 256, 0, stream>>>(H1b, w1, indptr, srcs,
                                            b1, g1, be1, mu1, var1, X2b, N);

  // --- Layer 2 ---
  gemm_bf16_kernel<<<dim3((N + 63) / 64, HID / 64), 256, 0, stream>>>(X2b, W2t, H2b, N, HID, C1);
  alpha2_kernel<<<(N + 3) / 4, 256, 0, stream>>>(H2b, a_src2, a_dst2, asrc2, adst2, N);
  edgew2_kernel<<<(Etot + 255) / 256, 256, 0, stream>>>(srcs, edst, asrc2, adst2, w2, Etot);
  gat2_agg<<<(N + 3) / 4, 256, 0, stream>>>(H2b, w2, indptr, srcs,
                                            b2, g2, be2, mu2, var2, out, N);
}

// Round 6
// 281.592 us; speedup vs baseline: 2.8047x; 1.3744x over previous
//
#include <hip/hip_runtime.h>

#define IN_DIM 256
#define HID 64
#define HEADS 4
#define C1 256   // HID*HEADS

typedef __attribute__((ext_vector_type(4))) float  f32x4;
typedef __attribute__((ext_vector_type(8))) short  short8;
typedef __attribute__((ext_vector_type(8))) unsigned short ushort8;
typedef __attribute__((ext_vector_type(4))) unsigned short ushort4v;

static __device__ __forceinline__ unsigned short f2bf(float f) {
  union { float f; unsigned int u; } v; v.f = f;
  unsigned int r = v.u + 0x7fffu + ((v.u >> 16) & 1u);   // RNE
  return (unsigned short)(r >> 16);
}
static __device__ __forceinline__ float bf2f(unsigned short u) {
  union { unsigned int u; float f; } v; v.u = ((unsigned int)u) << 16;
  return v.f;
}

// ---------------------------------------------------------------------------
// CSR build
// ---------------------------------------------------------------------------

__global__ __launch_bounds__(256) void zero_int_kernel(int* __restrict__ p, int n) {
  int i = blockIdx.x * 256 + threadIdx.x;
  if (i < n) p[i] = 0;
}

__global__ __launch_bounds__(256) void hist_kernel(const int* __restrict__ ei,
                                                   int E, int N, int* __restrict__ counts) {
  int e = blockIdx.x * 256 + threadIdx.x;
  if (e >= E + N) return;
  int dst = (e < E) ? ei[(size_t)E + e] : (e - E);
  atomicAdd(&counts[dst], 1);
}

// --- hierarchical scan: 1024 elements per block ---

__global__ __launch_bounds__(256) void scan1_kernel(const int* __restrict__ counts,
                                                    int* __restrict__ blocksums, int N) {
  int tid = threadIdx.x;
  int base = blockIdx.x * 1024 + tid * 4;
  int s = 0;
  if (base + 3 < N) {
    int4 v = *(const int4*)&counts[base];
    s = v.x + v.y + v.z + v.w;
  } else {
    for (int i = 0; i < 4; ++i) if (base + i < N) s += counts[base + i];
  }
  __shared__ int red[256];
  red[tid] = s;
  __syncthreads();
  for (int off = 128; off; off >>= 1) {
    if (tid < off) red[tid] += red[tid + off];
    __syncthreads();
  }
  if (tid == 0) blocksums[blockIdx.x] = red[0];
}

__global__ __launch_bounds__(64) void scan2_kernel(const int* __restrict__ blocksums,
                                                   int* __restrict__ blockoff, int B) {
  int lane = threadIdx.x;
  int carry = 0;
  for (int base = 0; base < B; base += 64) {
    int v = (base + lane < B) ? blocksums[base + lane] : 0;
    int incl = v;
    #pragma unroll
    for (int off = 1; off < 64; off <<= 1) {
      int t = __shfl_up(incl, off);
      if (lane >= off) incl += t;
    }
    if (base + lane < B) blockoff[base + lane] = carry + incl - v;
    carry += __shfl(incl, 63);
  }
  if (lane == 0) blockoff[B] = carry;   // grand total
}

__global__ __launch_bounds__(256) void scan3_kernel(const int* __restrict__ counts,
                                                    const int* __restrict__ blockoff,
                                                    int* __restrict__ indptr,
                                                    int* __restrict__ fillpos, int N) {
  int tid = threadIdx.x;
  int base = blockIdx.x * 1024 + tid * 4;
  int c0 = 0, c1 = 0, c2 = 0, c3 = 0;
  if (base + 3 < N) {
    int4 v = *(const int4*)&counts[base];
    c0 = v.x; c1 = v.y; c2 = v.z; c3 = v.w;
  } else {
    if (base + 0 < N) c0 = counts[base + 0];
    if (base + 1 < N) c1 = counts[base + 1];
    if (base + 2 < N) c2 = counts[base + 2];
    if (base + 3 < N) c3 = counts[base + 3];
  }
  int s = c0 + c1 + c2 + c3;
  __shared__ int sc[256];
  sc[tid] = s;
  __syncthreads();
  for (int off = 1; off < 256; off <<= 1) {
    int t = (tid >= off) ? sc[tid - off] : 0;
    __syncthreads();
    sc[tid] += t;
    __syncthreads();
  }
  int p = sc[tid] - s + blockoff[blockIdx.x];
  if (base + 0 < N) { indptr[base + 0] = p; fillpos[base + 0] = p; p += c0; }
  if (base + 1 < N) { indptr[base + 1] = p; fillpos[base + 1] = p; p += c1; }
  if (base + 2 < N) { indptr[base + 2] = p; fillpos[base + 2] = p; p += c2; }
  if (base + 3 < N) { indptr[base + 3] = p; fillpos[base + 3] = p; p += c3; }
  if (blockIdx.x == 0 && tid == 0) indptr[N] = blockoff[gridDim.x];
}

__global__ __launch_bounds__(256) void fill_kernel(const int* __restrict__ ei, int E, int N,
                                                   int* __restrict__ fillpos,
                                                   int* __restrict__ srcs,
                                                   int* __restrict__ edst) {
  int e = blockIdx.x * 256 + threadIdx.x;
  if (e >= E + N) return;
  int src, dst;
  if (e < E) { src = ei[e]; dst = ei[(size_t)E + e]; }
  else       { src = e - E; dst = e - E; }
  int pos = atomicAdd(&fillpos[dst], 1);
  srcs[pos] = src;
  edst[pos] = dst;
}

// ---------------------------------------------------------------------------
// Conversions: x -> bf16; W -> bf16 transposed ([n][k]) so GEMM A and B tiles
// share the identical [row][k] LDS pattern.
// ---------------------------------------------------------------------------

__global__ __launch_bounds__(256) void convx_kernel(const float* __restrict__ in,
                                                    unsigned short* __restrict__ outb, int n8) {
  int i = blockIdx.x * 256 + threadIdx.x;
  if (i >= n8) return;
  const float4* p = (const float4*)(in + (size_t)i * 8);
  float4 a = p[0], b = p[1];
  ushort8 o;
  o[0]=f2bf(a.x); o[1]=f2bf(a.y); o[2]=f2bf(a.z); o[3]=f2bf(a.w);
  o[4]=f2bf(b.x); o[5]=f2bf(b.y); o[6]=f2bf(b.z); o[7]=f2bf(b.w);
  *(ushort8*)(outb + (size_t)i * 8) = o;
}

// W[k][n] (f32, KxNC) -> Wt[n][k] (bf16, NCxK)
__global__ __launch_bounds__(256) void convwt_kernel(const float* __restrict__ W,
                                                     unsigned short* __restrict__ Wt,
                                                     int K, int NC) {
  int t = blockIdx.x * 256 + threadIdx.x;
  if (t >= K * NC) return;
  int k = t & (K - 1);      // K is 256 (pow2)
  int n = t >> 8;
  Wt[(size_t)n * K + k] = f2bf(W[(size_t)k * NC + n]);
}

// ---------------------------------------------------------------------------
// bf16 MFMA GEMM: C[M,NC](bf16) = A[M,K](bf16) @ Bt[NC,K](bf16, pre-transposed)
// BM=BN=64, BK=32; 4 waves, each 32x32 (2x2 frags of 16x16x32).
// ---------------------------------------------------------------------------

#define LDT 40   // padded LDS row stride (elements); 80B = 5*16B, aligned

__global__ __launch_bounds__(256) void gemm_bf16_kernel(const unsigned short* __restrict__ A,
                                                        const unsigned short* __restrict__ Bt,
                                                        unsigned short* __restrict__ C,
                                                        int M, int NC, int K) {
  __shared__ unsigned short As[64 * LDT];
  __shared__ unsigned short Bs[64 * LDT];
  int bm = blockIdx.x * 64, bn = blockIdx.y * 64;
  int tid = threadIdx.x;
  int wid = tid >> 6, lane = tid & 63;
  int wr = (wid >> 1) * 32, wc = (wid & 1) * 32;
  int lrow = tid >> 2;            // 0..63
  int lk   = (tid & 3) * 8;       // 0,8,16,24

  f32x4 acc00 = {0,0,0,0}, acc01 = {0,0,0,0}, acc10 = {0,0,0,0}, acc11 = {0,0,0,0};
  int l15 = lane & 15, lq = lane >> 4;

  for (int k0 = 0; k0 < K; k0 += 32) {
    int arow = bm + lrow;
    ushort8 av = {0,0,0,0,0,0,0,0};
    if (arow < M) av = *(const ushort8*)&A[(size_t)arow * K + k0 + lk];
    *(ushort8*)&As[lrow * LDT + lk] = av;
    ushort8 bv = *(const ushort8*)&Bt[(size_t)(bn + lrow) * K + k0 + lk];
    *(ushort8*)&Bs[lrow * LDT + lk] = bv;
    __syncthreads();

    short8 a0 = *(const short8*)&As[(wr + l15) * LDT + lq * 8];
    short8 a1 = *(const short8*)&As[(wr + 16 + l15) * LDT + lq * 8];
    short8 b0 = *(const short8*)&Bs[(wc + l15) * LDT + lq * 8];
    short8 b1 = *(const short8*)&Bs[(wc + 16 + l15) * LDT + lq * 8];
    acc00 = __builtin_amdgcn_mfma_f32_16x16x32_bf16(a0, b0, acc00, 0, 0, 0);
    acc01 = __builtin_amdgcn_mfma_f32_16x16x32_bf16(a0, b1, acc01, 0, 0, 0);
    acc10 = __builtin_amdgcn_mfma_f32_16x16x32_bf16(a1, b0, acc10, 0, 0, 0);
    acc11 = __builtin_amdgcn_mfma_f32_16x16x32_bf16(a1, b1, acc11, 0, 0, 0);
    __syncthreads();
  }

  // C/D layout (verified): col = lane&15, row = (lane>>4)*4 + reg
  #pragma unroll
  for (int r = 0; r < 4; ++r) {
    int row0 = bm + wr + lq * 4 + r;
    int row1 = row0 + 16;
    int colb = bn + wc + l15;
    if (row0 < M) {
      C[(size_t)row0 * NC + colb]      = f2bf(acc00[r]);
      C[(size_t)row0 * NC + colb + 16] = f2bf(acc01[r]);
    }
    if (row1 < M) {
      C[(size_t)row1 * NC + colb]      = f2bf(acc10[r]);
      C[(size_t)row1 * NC + colb + 16] = f2bf(acc11[r]);
    }
  }
}

// ---------------------------------------------------------------------------
// Attention logit projections (bf16 H)
// ---------------------------------------------------------------------------

// wave per node; lane covers feats 4l..4l+3 (256 feats)
__global__ __launch_bounds__(256) void alpha1_kernel(const unsigned short* __restrict__ H1b,
                                                     const float* __restrict__ a_src,
                                                     const float* __restrict__ a_dst,
                                                     float* __restrict__ asrc,
                                                     float* __restrict__ adst, int N) {
  int n = blockIdx.x * 4 + (threadIdx.x >> 6);
  if (n >= N) return;
  int lane = threadIdx.x & 63;
  int h = lane >> 4;
  ushort4v raw = *(const ushort4v*)&H1b[(size_t)n * C1 + lane * 4];
  float4 as = *(const float4*)&a_src[h * HID + (lane & 15) * 4];
  float4 ad = *(const float4*)&a_dst[h * HID + (lane & 15) * 4];
  float h0 = bf2f(raw[0]), h1 = bf2f(raw[1]), h2 = bf2f(raw[2]), h3 = bf2f(raw[3]);
  float vs = h0 * as.x + h1 * as.y + h2 * as.z + h3 * as.w;
  float vd = h0 * ad.x + h1 * ad.y + h2 * ad.z + h3 * ad.w;
  #pragma unroll
  for (int off = 1; off < 16; off <<= 1) {
    vs += __shfl_xor(vs, off);
    vd += __shfl_xor(vd, off);
  }
  if ((lane & 15) == 0) {
    asrc[n * HEADS + h] = vs;
    adst[n * HEADS + h] = vd;
  }
}

// wave per node; lanes use l&31 (duplicated halves), feats 2j..2j+1
__global__ __launch_bounds__(256) void alpha2_kernel(const unsigned short* __restrict__ H2b,
                                                     const float* __restrict__ a_src,
                                                     const float* __restrict__ a_dst,
                                                     float* __restrict__ asrc,
                                                     float* __restrict__ adst, int N) {
  int n = blockIdx.x * 4 + (threadIdx.x >> 6);
  if (n >= N) return;
  int lane = threadIdx.x & 63;
  int j = lane & 31;
  unsigned int raw = *(const unsigned int*)&H2b[(size_t)n * HID + j * 2];
  float h0 = bf2f((unsigned short)(raw & 0xffff));
  float h1 = bf2f((unsigned short)(raw >> 16));
  float vs = h0 * a_src[j * 2] + h1 * a_src[j * 2 + 1];
  float vd = h0 * a_dst[j * 2] + h1 * a_dst[j * 2 + 1];
  #pragma unroll
  for (int off = 1; off < 32; off <<= 1) {
    vs += __shfl_xor(vs, off);
    vd += __shfl_xor(vd, off);
  }
  if (lane == 0) { asrc[n] = vs; adst[n] = vd; }
}

// ---------------------------------------------------------------------------
// Edge softmax weights — streaming, no atomics
// ---------------------------------------------------------------------------

__global__ __launch_bounds__(256) void edgew1_kernel(const int* __restrict__ srcs,
                                                     const int* __restrict__ edst,
                                                     const float* __restrict__ asrc,
                                                     const float* __restrict__ adst,
                                                     float* __restrict__ w, int Etot) {
  int k = blockIdx.x * 256 + threadIdx.x;
  if (k >= Etot) return;
  int s = srcs[k], d = edst[k];
  float4 as = *(const float4*)&asrc[s * 4];
  float4 ad = *(const float4*)&adst[d * 4];
  float e0 = as.x + ad.x; e0 = (e0 > 0.f) ? e0 : 0.2f * e0;
  float e1 = as.y + ad.y; e1 = (e1 > 0.f) ? e1 : 0.2f * e1;
  float e2 = as.z + ad.z; e2 = (e2 > 0.f) ? e2 : 0.2f * e2;
  float e3 = as.w + ad.w; e3 = (e3 > 0.f) ? e3 : 0.2f * e3;
  *(float4*)&w[k * 4] = make_float4(__expf(e0), __expf(e1), __expf(e2), __expf(e3));
}

__global__ __launch_bounds__(256) void edgew2_kernel(const int* __restrict__ srcs,
                                                     const int* __restrict__ edst,
                                                     const float* __restrict__ asrc,
                                                     const float* __restrict__ adst,
                                                     float* __restrict__ w, int Etot) {
  int k = blockIdx.x * 256 + threadIdx.x;
  if (k >= Etot) return;
  float e = asrc[srcs[k]] + adst[edst[k]];
  e = (e > 0.f) ? e : 0.2f * e;
  w[k] = __expf(e);
}

// ---------------------------------------------------------------------------
// GAT agg layer 1 (bf16 H1): wave per node, split-wave 2 edges/iter.
// lane = (half = l>>5, j = l&31); lane covers feats 8j..8j+7 (16B read).
// ---------------------------------------------------------------------------

__global__ __launch_bounds__(256) void gat1_agg(const unsigned short* __restrict__ H1b,
                                                const float* __restrict__ w,
                                                const int* __restrict__ indptr,
                                                const int* __restrict__ srcs,
                                                const float* __restrict__ b1,
                                                const float* __restrict__ g1,
                                                const float* __restrict__ be1,
                                                const float* __restrict__ mu1,
                                                const float* __restrict__ var1,
                                                unsigned short* __restrict__ X2b, int N) {
  int n = blockIdx.x * 4 + (threadIdx.x >> 6);
  if (n >= N) return;
  int lane = threadIdx.x & 63;
  int half = lane >> 5;
  int j = lane & 31;
  int h = j >> 3;
  int start = indptr[n], end = indptr[n + 1];

  float acc[8] = {0.f,0.f,0.f,0.f,0.f,0.f,0.f,0.f};
  float wsum = 0.f;
  for (int k = start + half; k < end; k += 2) {
    int s = srcs[k];
    float wt = w[k * 4 + h];
    ushort8 raw = *(const ushort8*)&H1b[(size_t)s * C1 + j * 8];
    wsum += wt;
    #pragma unroll
    for (int i = 0; i < 8; ++i) acc[i] += wt * bf2f(raw[i]);
  }
  #pragma unroll
  for (int i = 0; i < 8; ++i) acc[i] += __shfl_xor(acc[i], 32);
  wsum += __shfl_xor(wsum, 32);

  if (half == 0) {
    float inv = 1.f / (wsum + 1e-16f);
    int f = j * 8;
    float4 bb0 = *(const float4*)&b1[f],   bb1 = *(const float4*)&b1[f + 4];
    float4 gg0 = *(const float4*)&g1[f],   gg1 = *(const float4*)&g1[f + 4];
    float4 ee0 = *(const float4*)&be1[f],  ee1 = *(const float4*)&be1[f + 4];
    float4 mm0 = *(const float4*)&mu1[f],  mm1 = *(const float4*)&mu1[f + 4];
    float4 vv0 = *(const float4*)&var1[f], vv1 = *(const float4*)&var1[f + 4];
    float bbv[8] = {bb0.x,bb0.y,bb0.z,bb0.w, bb1.x,bb1.y,bb1.z,bb1.w};
    float ggv[8] = {gg0.x,gg0.y,gg0.z,gg0.w, gg1.x,gg1.y,gg1.z,gg1.w};
    float eev[8] = {ee0.x,ee0.y,ee0.z,ee0.w, ee1.x,ee1.y,ee1.z,ee1.w};
    float mmv[8] = {mm0.x,mm0.y,mm0.z,mm0.w, mm1.x,mm1.y,mm1.z,mm1.w};
    float vvv[8] = {vv0.x,vv0.y,vv0.z,vv0.w, vv1.x,vv1.y,vv1.z,vv1.w};
    ushort8 o;
    #pragma unroll
    for (int i = 0; i < 8; ++i) {
      float val = (acc[i] * inv + bbv[i] - mmv[i]) * (ggv[i] * rsqrtf(vvv[i] + 1e-5f)) + eev[i];
      val = (val > 0.f) ? val : (__expf(val) - 1.f);
      o[i] = f2bf(val);
    }
    *(ushort8*)&X2b[(size_t)n * C1 + f] = o;
  }
}

// ---------------------------------------------------------------------------
// GAT agg layer 2 (bf16 H2): wave per node, quarter-wave 4 edges/iter.
// lane = (q = l>>4, j = l&15); lane covers feats 4j..4j+3 (8B read). f32 out.
// ---------------------------------------------------------------------------

__global__ __launch_bounds__(256) void gat2_agg(const unsigned short* __restrict__ H2b,
                                                const float* __restrict__ w,
                                                const int* __restrict__ indptr,
                                                const int* __restrict__ srcs,
                                                const float* __restrict__ b2,
                                                const float* __restrict__ g2,
                                                const float* __restrict__ be2,
                                                const float* __restrict__ mu2,
                                                const float* __restrict__ var2,
                                                float* __restrict__ out, int N) {
  int n = blockIdx.x * 4 + (threadIdx.x >> 6);
  if (n >= N) return;
  int lane = threadIdx.x & 63;
  int q = lane >> 4;
  int j = lane & 15;
  int start = indptr[n], end = indptr[n + 1];

  float acc[4] = {0.f,0.f,0.f,0.f};
  float wsum = 0.f;
  for (int k = start + q; k < end; k += 4) {
    int s = srcs[k];
    float wt = w[k];
    ushort4v raw = *(const ushort4v*)&H2b[(size_t)s * HID + j * 4];
    wsum += wt;
    #pragma unroll
    for (int i = 0; i < 4; ++i) acc[i] += wt * bf2f(raw[i]);
  }
  #pragma unroll
  for (int i = 0; i < 4; ++i) {
    acc[i] += __shfl_xor(acc[i], 16);
    acc[i] += __shfl_xor(acc[i], 32);
  }
  wsum += __shfl_xor(wsum, 16);
  wsum += __shfl_xor(wsum, 32);

  if (q == 0) {
    float inv = 1.f / (wsum + 1e-16f);
    int f = j * 4;
    float4 bb = *(const float4*)&b2[f];
    float4 gg = *(const float4*)&g2[f];
    float4 ee = *(const float4*)&be2[f];
    float4 mm = *(const float4*)&mu2[f];
    float4 vv = *(const float4*)&var2[f];
    float4 val;
    val.x = (acc[0] * inv + bb.x - mm.x) * (gg.x * rsqrtf(vv.x + 1e-5f)) + ee.x;
    val.y = (acc[1] * inv + bb.y - mm.y) * (gg.y * rsqrtf(vv.y + 1e-5f)) + ee.y;
    val.z = (acc[2] * inv + bb.z - mm.z) * (gg.z * rsqrtf(vv.z + 1e-5f)) + ee.z;
    val.w = (acc[3] * inv + bb.w - mm.w) * (gg.w * rsqrtf(vv.w + 1e-5f)) + ee.w;
    val.x = (val.x > 0.f) ? val.x : (__expf(val.x) - 1.f);
    val.y = (val.y > 0.f) ? val.y : (__expf(val.y) - 1.f);
    val.z = (val.z > 0.f) ? val.z : (__expf(val.z) - 1.f);
    val.w = (val.w > 0.f) ? val.w : (__expf(val.w) - 1.f);
    *(float4*)&out[(size_t)n * HID + f] = val;
  }
}

// ---------------------------------------------------------------------------

extern "C" void kernel_launch(void* const* d_in, const int* in_sizes, int n_in,
                              void* d_out, int out_size, void* d_ws, size_t ws_size,
                              hipStream_t stream) {
  const float* x      = (const float*)d_in[0];
  const int*   ei     = (const int*)d_in[1];
  const float* W1     = (const float*)d_in[2];
  const float* a_src1 = (const float*)d_in[3];
  const float* a_dst1 = (const float*)d_in[4];
  const float* b1     = (const float*)d_in[5];
  const float* g1     = (const float*)d_in[6];
  const float* be1    = (const float*)d_in[7];
  const float* mu1    = (const float*)d_in[8];
  const float* var1   = (const float*)d_in[9];
  const float* W2     = (const float*)d_in[10];
  const float* a_src2 = (const float*)d_in[11];
  const float* a_dst2 = (const float*)d_in[12];
  const float* b2     = (const float*)d_in[13];
  const float* g2     = (const float*)d_in[14];
  const float* be2    = (const float*)d_in[15];
  const float* mu2    = (const float*)d_in[16];
  const float* var2   = (const float*)d_in[17];
  float* out = (float*)d_out;

  int N = in_sizes[0] / IN_DIM;
  int E = in_sizes[1] / 2;
  int Etot = E + N;
  int NB = (N + 1023) / 1024;   // scan blocks

  // Workspace (~100 MB):
  //   xb[N*256]b | H1b[N*256]b (reused as H2b) | X2b[N*256]b | W1t[256*256]b |
  //   W2t[64*256]b | w1[4*Etot]f (reused as w2) | asrc1[4N]f | adst1[4N]f |
  //   asrc2[N]f | adst2[N]f | counts[N] | indptr[N+1] | fillpos[N] |
  //   blocksums[NB] | blockoff[NB+1] | srcs[Etot] | edst[Etot]
  unsigned short* xb  = (unsigned short*)d_ws;
  unsigned short* H1b = xb  + (size_t)N * C1;
  unsigned short* X2b = H1b + (size_t)N * C1;
  unsigned short* W1t = X2b + (size_t)N * C1;
  unsigned short* W2t = W1t + 256 * 256;
  float* w1    = (float*)(W2t + 64 * 256);
  float* asrc1 = w1 + (size_t)4 * Etot;
  float* adst1 = asrc1 + (size_t)N * HEADS;
  float* asrc2 = adst1 + (size_t)N * HEADS;
  float* adst2 = asrc2 + N;
  int* counts    = (int*)(adst2 + N);
  int* indptr    = counts + N;
  int* fillpos   = indptr + (N + 1);
  int* blocksums = fillpos + N;
  int* blockoff  = blocksums + NB;
  int* srcs      = blockoff + (NB + 1);
  int* edst      = srcs + Etot;
  unsigned short* H2b = H1b;   // H1b dead after gat1_agg
  float* w2 = w1;              // w1 dead before edgew2

  // --- CSR build (hierarchical scan) ---
  zero_int_kernel<<<(N + 255) / 256, 256, 0, stream>>>(counts, N);
  hist_kernel<<<(Etot + 255) / 256, 256, 0, stream>>>(ei, E, N, counts);
  scan1_kernel<<<NB, 256, 0, stream>>>(counts, blocksums, N);
  scan2_kernel<<<1, 64, 0, stream>>>(blocksums, blockoff, NB);
  scan3_kernel<<<NB, 256, 0, stream>>>(counts, blockoff, indptr, fillpos, N);
  fill_kernel<<<(Etot + 255) / 256, 256, 0, stream>>>(ei, E, N, fillpos, srcs, edst);

  // --- Conversions ---
  int n8 = N * C1 / 8;
  convx_kernel<<<(n8 + 255) / 256, 256, 0, stream>>>(x, xb, n8);
  convwt_kernel<<<(256 * 256 + 255) / 256, 256, 0, stream>>>(W1, W1t, 256, C1);
  convwt_kernel<<<(256 * 64 + 255) / 256, 256, 0, stream>>>(W2, W2t, 256, HID);

  // --- Layer 1 ---
  gemm_bf16_kernel<<<dim3((N + 63) / 64, C1 / 64), 256, 0, stream>>>(xb, W1t, H1b, N, C1, IN_DIM);
  alpha1_kernel<<<(N + 3) / 4, 256, 0, stream>>>(H1b, a_src1, a_dst1, asrc1, adst1, N);
  edgew1_kernel<<<(Etot + 255) / 256, 256, 0, stream>>>(srcs, edst, asrc1, adst1, w1, Etot);
  gat1_agg<<<(N + 3) / 4, 256, 0, stream>>>(H1b, w1, indptr, srcs,
                                            b1, g1, be1, mu1, var1, X2b, N);

  // --- Layer 2 ---
  gemm_bf16_kernel<<<dim3((N + 63) / 64, HID / 64), 256, 0, stream>>>(X2b, W2t, H2b, N, HID, C1);
  alpha2_kernel<<<(N + 3) / 4, 256, 0, stream>>>(H2b, a_src2, a_dst2, asrc2, adst2, N);
  edgew2_kernel<<<(Etot + 255) / 256, 256, 0, stream>>>(srcs, edst, asrc2, adst2, w2, Etot);
  gat2_agg<<<(N + 3) / 4, 256, 0, stream>>>(H2b, w2, indptr, srcs,
                                            b2, g2, be2, mu2, var2, out, N);
}

// Round 7
// 275.203 us; speedup vs baseline: 2.8698x; 1.0232x over previous
//
#include <hip/hip_runtime.h>

#define IN_DIM 256
#define HID 64
#define HEADS 4
#define C1 256   // HID*HEADS

typedef __attribute__((ext_vector_type(4))) float  f32x4;
typedef __attribute__((ext_vector_type(8))) short  short8;
typedef __attribute__((ext_vector_type(8))) unsigned short ushort8;
typedef __attribute__((ext_vector_type(4))) unsigned short ushort4v;

static __device__ __forceinline__ unsigned short f2bf(float f) {
  union { float f; unsigned int u; } v; v.f = f;
  unsigned int r = v.u + 0x7fffu + ((v.u >> 16) & 1u);   // RNE
  return (unsigned short)(r >> 16);
}
static __device__ __forceinline__ float bf2f(unsigned short u) {
  union { unsigned int u; float f; } v; v.u = ((unsigned int)u) << 16;
  return v.f;
}

// ---------------------------------------------------------------------------
// CSR build
// ---------------------------------------------------------------------------

__global__ __launch_bounds__(256) void zero_int_kernel(int* __restrict__ p, int n) {
  int i = blockIdx.x * 256 + threadIdx.x;
  if (i < n) p[i] = 0;
}

__global__ __launch_bounds__(256) void hist_kernel(const int* __restrict__ ei,
                                                   int E, int N, int* __restrict__ counts) {
  int e = blockIdx.x * 256 + threadIdx.x;
  if (e >= E + N) return;
  int dst = (e < E) ? ei[(size_t)E + e] : (e - E);
  atomicAdd(&counts[dst], 1);
}

// --- hierarchical scan: 1024 elements per block ---

__global__ __launch_bounds__(256) void scan1_kernel(const int* __restrict__ counts,
                                                    int* __restrict__ blocksums, int N) {
  int tid = threadIdx.x;
  int base = blockIdx.x * 1024 + tid * 4;
  int s = 0;
  if (base + 3 < N) {
    int4 v = *(const int4*)&counts[base];
    s = v.x + v.y + v.z + v.w;
  } else {
    for (int i = 0; i < 4; ++i) if (base + i < N) s += counts[base + i];
  }
  __shared__ int red[256];
  red[tid] = s;
  __syncthreads();
  for (int off = 128; off; off >>= 1) {
    if (tid < off) red[tid] += red[tid + off];
    __syncthreads();
  }
  if (tid == 0) blocksums[blockIdx.x] = red[0];
}

__global__ __launch_bounds__(64) void scan2_kernel(const int* __restrict__ blocksums,
                                                   int* __restrict__ blockoff, int B) {
  int lane = threadIdx.x;
  int carry = 0;
  for (int base = 0; base < B; base += 64) {
    int v = (base + lane < B) ? blocksums[base + lane] : 0;
    int incl = v;
    #pragma unroll
    for (int off = 1; off < 64; off <<= 1) {
      int t = __shfl_up(incl, off);
      if (lane >= off) incl += t;
    }
    if (base + lane < B) blockoff[base + lane] = carry + incl - v;
    carry += __shfl(incl, 63);
  }
  if (lane == 0) blockoff[B] = carry;   // grand total
}

__global__ __launch_bounds__(256) void scan3_kernel(const int* __restrict__ counts,
                                                    const int* __restrict__ blockoff,
                                                    int* __restrict__ indptr,
                                                    int* __restrict__ fillpos, int N) {
  int tid = threadIdx.x;
  int base = blockIdx.x * 1024 + tid * 4;
  int c0 = 0, c1 = 0, c2 = 0, c3 = 0;
  if (base + 3 < N) {
    int4 v = *(const int4*)&counts[base];
    c0 = v.x; c1 = v.y; c2 = v.z; c3 = v.w;
  } else {
    if (base + 0 < N) c0 = counts[base + 0];
    if (base + 1 < N) c1 = counts[base + 1];
    if (base + 2 < N) c2 = counts[base + 2];
    if (base + 3 < N) c3 = counts[base + 3];
  }
  int s = c0 + c1 + c2 + c3;
  __shared__ int sc[256];
  sc[tid] = s;
  __syncthreads();
  for (int off = 1; off < 256; off <<= 1) {
    int t = (tid >= off) ? sc[tid - off] : 0;
    __syncthreads();
    sc[tid] += t;
    __syncthreads();
  }
  int p = sc[tid] - s + blockoff[blockIdx.x];
  if (base + 0 < N) { indptr[base + 0] = p; fillpos[base + 0] = p; p += c0; }
  if (base + 1 < N) { indptr[base + 1] = p; fillpos[base + 1] = p; p += c1; }
  if (base + 2 < N) { indptr[base + 2] = p; fillpos[base + 2] = p; p += c2; }
  if (base + 3 < N) { indptr[base + 3] = p; fillpos[base + 3] = p; p += c3; }
  if (blockIdx.x == 0 && tid == 0) indptr[N] = blockoff[gridDim.x];
}

__global__ __launch_bounds__(256) void fill_kernel(const int* __restrict__ ei, int E, int N,
                                                   int* __restrict__ fillpos,
                                                   int* __restrict__ srcs) {
  int e = blockIdx.x * 256 + threadIdx.x;
  if (e >= E + N) return;
  int src, dst;
  if (e < E) { src = ei[e]; dst = ei[(size_t)E + e]; }
  else       { src = e - E; dst = e - E; }
  int pos = atomicAdd(&fillpos[dst], 1);
  srcs[pos] = src;
}

// ---------------------------------------------------------------------------
// Conversions
// ---------------------------------------------------------------------------

__global__ __launch_bounds__(256) void convx_kernel(const float* __restrict__ in,
                                                    unsigned short* __restrict__ outb, int n8) {
  int i = blockIdx.x * 256 + threadIdx.x;
  if (i >= n8) return;
  const float4* p = (const float4*)(in + (size_t)i * 8);
  float4 a = p[0], b = p[1];
  ushort8 o;
  o[0]=f2bf(a.x); o[1]=f2bf(a.y); o[2]=f2bf(a.z); o[3]=f2bf(a.w);
  o[4]=f2bf(b.x); o[5]=f2bf(b.y); o[6]=f2bf(b.z); o[7]=f2bf(b.w);
  *(ushort8*)(outb + (size_t)i * 8) = o;
}

// W[k][n] (f32, KxNC) -> Wt[n][k] (bf16, NCxK)
__global__ __launch_bounds__(256) void convwt_kernel(const float* __restrict__ W,
                                                     unsigned short* __restrict__ Wt,
                                                     int K, int NC) {
  int t = blockIdx.x * 256 + threadIdx.x;
  if (t >= K * NC) return;
  int k = t & (K - 1);      // K is 256 (pow2)
  int n = t >> 8;
  Wt[(size_t)n * K + k] = f2bf(W[(size_t)k * NC + n]);
}

// ---------------------------------------------------------------------------
// bf16 MFMA GEMM: C[M,NC](bf16) = A[M,K](bf16) @ Bt[NC,K](bf16, pre-transposed)
// BM=BN=64, BK=32; 4 waves, each 32x32 (2x2 frags of 16x16x32).
// ---------------------------------------------------------------------------

#define LDT 40   // padded LDS row stride (elements)

__global__ __launch_bounds__(256) void gemm_bf16_kernel(const unsigned short* __restrict__ A,
                                                        const unsigned short* __restrict__ Bt,
                                                        unsigned short* __restrict__ C,
                                                        int M, int NC, int K) {
  __shared__ unsigned short As[64 * LDT];
  __shared__ unsigned short Bs[64 * LDT];
  int bm = blockIdx.x * 64, bn = blockIdx.y * 64;
  int tid = threadIdx.x;
  int wid = tid >> 6, lane = tid & 63;
  int wr = (wid >> 1) * 32, wc = (wid & 1) * 32;
  int lrow = tid >> 2;            // 0..63
  int lk   = (tid & 3) * 8;       // 0,8,16,24

  f32x4 acc00 = {0,0,0,0}, acc01 = {0,0,0,0}, acc10 = {0,0,0,0}, acc11 = {0,0,0,0};
  int l15 = lane & 15, lq = lane >> 4;

  for (int k0 = 0; k0 < K; k0 += 32) {
    int arow = bm + lrow;
    ushort8 av = {0,0,0,0,0,0,0,0};
    if (arow < M) av = *(const ushort8*)&A[(size_t)arow * K + k0 + lk];
    *(ushort8*)&As[lrow * LDT + lk] = av;
    ushort8 bv = *(const ushort8*)&Bt[(size_t)(bn + lrow) * K + k0 + lk];
    *(ushort8*)&Bs[lrow * LDT + lk] = bv;
    __syncthreads();

    short8 a0 = *(const short8*)&As[(wr + l15) * LDT + lq * 8];
    short8 a1 = *(const short8*)&As[(wr + 16 + l15) * LDT + lq * 8];
    short8 b0 = *(const short8*)&Bs[(wc + l15) * LDT + lq * 8];
    short8 b1 = *(const short8*)&Bs[(wc + 16 + l15) * LDT + lq * 8];
    acc00 = __builtin_amdgcn_mfma_f32_16x16x32_bf16(a0, b0, acc00, 0, 0, 0);
    acc01 = __builtin_amdgcn_mfma_f32_16x16x32_bf16(a0, b1, acc01, 0, 0, 0);
    acc10 = __builtin_amdgcn_mfma_f32_16x16x32_bf16(a1, b0, acc10, 0, 0, 0);
    acc11 = __builtin_amdgcn_mfma_f32_16x16x32_bf16(a1, b1, acc11, 0, 0, 0);
    __syncthreads();
  }

  #pragma unroll
  for (int r = 0; r < 4; ++r) {
    int row0 = bm + wr + lq * 4 + r;
    int row1 = row0 + 16;
    int colb = bn + wc + l15;
    if (row0 < M) {
      C[(size_t)row0 * NC + colb]      = f2bf(acc00[r]);
      C[(size_t)row0 * NC + colb + 16] = f2bf(acc01[r]);
    }
    if (row1 < M) {
      C[(size_t)row1 * NC + colb]      = f2bf(acc10[r]);
      C[(size_t)row1 * NC + colb + 16] = f2bf(acc11[r]);
    }
  }
}

// ---------------------------------------------------------------------------
// Attention logit projections (bf16 H)
// ---------------------------------------------------------------------------

__global__ __launch_bounds__(256) void alpha1_kernel(const unsigned short* __restrict__ H1b,
                                                     const float* __restrict__ a_src,
                                                     const float* __restrict__ a_dst,
                                                     float* __restrict__ asrc,
                                                     float* __restrict__ adst, int N) {
  int n = blockIdx.x * 4 + (threadIdx.x >> 6);
  if (n >= N) return;
  int lane = threadIdx.x & 63;
  int h = lane >> 4;
  ushort4v raw = *(const ushort4v*)&H1b[(size_t)n * C1 + lane * 4];
  float4 as = *(const float4*)&a_src[h * HID + (lane & 15) * 4];
  float4 ad = *(const float4*)&a_dst[h * HID + (lane & 15) * 4];
  float h0 = bf2f(raw[0]), h1 = bf2f(raw[1]), h2 = bf2f(raw[2]), h3 = bf2f(raw[3]);
  float vs = h0 * as.x + h1 * as.y + h2 * as.z + h3 * as.w;
  float vd = h0 * ad.x + h1 * ad.y + h2 * ad.z + h3 * ad.w;
  #pragma unroll
  for (int off = 1; off < 16; off <<= 1) {
    vs += __shfl_xor(vs, off);
    vd += __shfl_xor(vd, off);
  }
  if ((lane & 15) == 0) {
    asrc[n * HEADS + h] = vs;
    adst[n * HEADS + h] = vd;
  }
}

__global__ __launch_bounds__(256) void alpha2_kernel(const unsigned short* __restrict__ H2b,
                                                     const float* __restrict__ a_src,
                                                     const float* __restrict__ a_dst,
                                                     float* __restrict__ asrc,
                                                     float* __restrict__ adst, int N) {
  int n = blockIdx.x * 4 + (threadIdx.x >> 6);
  if (n >= N) return;
  int lane = threadIdx.x & 63;
  int j = lane & 31;
  unsigned int raw = *(const unsigned int*)&H2b[(size_t)n * HID + j * 2];
  float h0 = bf2f((unsigned short)(raw & 0xffff));
  float h1 = bf2f((unsigned short)(raw >> 16));
  float vs = h0 * a_src[j * 2] + h1 * a_src[j * 2 + 1];
  float vd = h0 * a_dst[j * 2] + h1 * a_dst[j * 2 + 1];
  #pragma unroll
  for (int off = 1; off < 32; off <<= 1) {
    vs += __shfl_xor(vs, off);
    vd += __shfl_xor(vd, off);
  }
  if (lane == 0) { asrc[n] = vs; adst[n] = vd; }
}

// ---------------------------------------------------------------------------
// GAT agg layer 1 (fused edge softmax): wave per node, 4 edges/iter.
// lane = (q = l>>4 edge slot, j = l&15 feat group); feats 16j..16j+15 (32B).
// ---------------------------------------------------------------------------

__global__ __launch_bounds__(256) void gat1_agg(const unsigned short* __restrict__ H1b,
                                                const float* __restrict__ asrc,
                                                const float* __restrict__ adst,
                                                const int* __restrict__ indptr,
                                                const int* __restrict__ srcs,
                                                const float* __restrict__ b1,
                                                const float* __restrict__ g1,
                                                const float* __restrict__ be1,
                                                const float* __restrict__ mu1,
                                                const float* __restrict__ var1,
                                                unsigned short* __restrict__ X2b, int N) {
  int n = blockIdx.x * 4 + (threadIdx.x >> 6);
  if (n >= N) return;
  int lane = threadIdx.x & 63;
  int q = lane >> 4;
  int j = lane & 15;
  int h = j >> 2;                      // head = (16j)/64
  int start = indptr[n], end = indptr[n + 1];
  float ad = adst[n * HEADS + h];

  float acc[16];
  #pragma unroll
  for (int i = 0; i < 16; ++i) acc[i] = 0.f;
  float wsum = 0.f;

  for (int k = start + q; k < end; k += 4) {
    int s = srcs[k];
    float e = asrc[s * HEADS + h] + ad;
    e = (e > 0.f) ? e : 0.2f * e;
    float wt = __expf(e);
    wsum += wt;
    const ushort8* p = (const ushort8*)&H1b[(size_t)s * C1 + j * 16];
    ushort8 r0 = p[0], r1 = p[1];
    #pragma unroll
    for (int i = 0; i < 8; ++i) {
      acc[i]     += wt * bf2f(r0[i]);
      acc[8 + i] += wt * bf2f(r1[i]);
    }
  }
  #pragma unroll
  for (int i = 0; i < 16; ++i) {
    acc[i] += __shfl_xor(acc[i], 16);
    acc[i] += __shfl_xor(acc[i], 32);
  }
  wsum += __shfl_xor(wsum, 16);
  wsum += __shfl_xor(wsum, 32);

  if (q == 0) {
    float inv = 1.f / (wsum + 1e-16f);
    int f = j * 16;
    ushort8 o0, o1;
    #pragma unroll
    for (int i = 0; i < 16; ++i) {
      float val = (acc[i] * inv + b1[f + i] - mu1[f + i]) *
                  (g1[f + i] * rsqrtf(var1[f + i] + 1e-5f)) + be1[f + i];
      val = (val > 0.f) ? val : (__expf(val) - 1.f);
      if (i < 8) o0[i] = f2bf(val); else o1[i - 8] = f2bf(val);
    }
    *(ushort8*)&X2b[(size_t)n * C1 + f]     = o0;
    *(ushort8*)&X2b[(size_t)n * C1 + f + 8] = o1;
  }
}

// ---------------------------------------------------------------------------
// GAT agg layer 2 (fused edge softmax): wave per node, 8 edges/iter.
// lane = (q = l>>3 edge slot, j = l&7 feat group); feats 8j..8j+7 (16B).
// ---------------------------------------------------------------------------

__global__ __launch_bounds__(256) void gat2_agg(const unsigned short* __restrict__ H2b,
                                                const float* __restrict__ asrc,
                                                const float* __restrict__ adst,
                                                const int* __restrict__ indptr,
                                                const int* __restrict__ srcs,
                                                const float* __restrict__ b2,
                                                const float* __restrict__ g2,
                                                const float* __restrict__ be2,
                                                const float* __restrict__ mu2,
                                                const float* __restrict__ var2,
                                                float* __restrict__ out, int N) {
  int n = blockIdx.x * 4 + (threadIdx.x >> 6);
  if (n >= N) return;
  int lane = threadIdx.x & 63;
  int q = lane >> 3;
  int j = lane & 7;
  int start = indptr[n], end = indptr[n + 1];
  float ad = adst[n];

  float acc[8];
  #pragma unroll
  for (int i = 0; i < 8; ++i) acc[i] = 0.f;
  float wsum = 0.f;

  for (int k = start + q; k < end; k += 8) {
    int s = srcs[k];
    float e = asrc[s] + ad;
    e = (e > 0.f) ? e : 0.2f * e;
    float wt = __expf(e);
    wsum += wt;
    ushort8 raw = *(const ushort8*)&H2b[(size_t)s * HID + j * 8];
    #pragma unroll
    for (int i = 0; i < 8; ++i) acc[i] += wt * bf2f(raw[i]);
  }
  #pragma unroll
  for (int i = 0; i < 8; ++i) {
    acc[i] += __shfl_xor(acc[i], 8);
    acc[i] += __shfl_xor(acc[i], 16);
    acc[i] += __shfl_xor(acc[i], 32);
  }
  wsum += __shfl_xor(wsum, 8);
  wsum += __shfl_xor(wsum, 16);
  wsum += __shfl_xor(wsum, 32);

  if (q == 0) {
    float inv = 1.f / (wsum + 1e-16f);
    int f = j * 8;
    float o[8];
    #pragma unroll
    for (int i = 0; i < 8; ++i) {
      float val = (acc[i] * inv + b2[f + i] - mu2[f + i]) *
                  (g2[f + i] * rsqrtf(var2[f + i] + 1e-5f)) + be2[f + i];
      o[i] = (val > 0.f) ? val : (__expf(val) - 1.f);
    }
    *(float4*)&out[(size_t)n * HID + f]     = make_float4(o[0], o[1], o[2], o[3]);
    *(float4*)&out[(size_t)n * HID + f + 4] = make_float4(o[4], o[5], o[6], o[7]);
  }
}

// ---------------------------------------------------------------------------

extern "C" void kernel_launch(void* const* d_in, const int* in_sizes, int n_in,
                              void* d_out, int out_size, void* d_ws, size_t ws_size,
                              hipStream_t stream) {
  const float* x      = (const float*)d_in[0];
  const int*   ei     = (const int*)d_in[1];
  const float* W1     = (const float*)d_in[2];
  const float* a_src1 = (const float*)d_in[3];
  const float* a_dst1 = (const float*)d_in[4];
  const float* b1     = (const float*)d_in[5];
  const float* g1     = (const float*)d_in[6];
  const float* be1    = (const float*)d_in[7];
  const float* mu1    = (const float*)d_in[8];
  const float* var1   = (const float*)d_in[9];
  const float* W2     = (const float*)d_in[10];
  const float* a_src2 = (const float*)d_in[11];
  const float* a_dst2 = (const float*)d_in[12];
  const float* b2     = (const float*)d_in[13];
  const float* g2     = (const float*)d_in[14];
  const float* be2    = (const float*)d_in[15];
  const float* mu2    = (const float*)d_in[16];
  const float* var2   = (const float*)d_in[17];
  float* out = (float*)d_out;

  int N = in_sizes[0] / IN_DIM;
  int E = in_sizes[1] / 2;
  int Etot = E + N;
  int NB = (N + 1023) / 1024;   // scan blocks

  // Workspace (~83 MB):
  //   xb[N*256]b | H1b[N*256]b (reused as H2b) | X2b[N*256]b | W1t[256*256]b |
  //   W2t[64*256]b | asrc1[4N]f | adst1[4N]f | asrc2[N]f | adst2[N]f |
  //   counts[N] | indptr[N+1] | fillpos[N] | blocksums[NB] | blockoff[NB+1] |
  //   srcs[Etot]
  unsigned short* xb  = (unsigned short*)d_ws;
  unsigned short* H1b = xb  + (size_t)N * C1;
  unsigned short* X2b = H1b + (size_t)N * C1;
  unsigned short* W1t = X2b + (size_t)N * C1;
  unsigned short* W2t = W1t + 256 * 256;
  float* asrc1 = (float*)(W2t + 64 * 256);
  float* adst1 = asrc1 + (size_t)N * HEADS;
  float* asrc2 = adst1 + (size_t)N * HEADS;
  float* adst2 = asrc2 + N;
  int* counts    = (int*)(adst2 + N);
  int* indptr    = counts + N;
  int* fillpos   = indptr + (N + 1);
  int* blocksums = fillpos + N;
  int* blockoff  = blocksums + NB;
  int* srcs      = blockoff + (NB + 1);
  unsigned short* H2b = H1b;   // H1b dead after gat1_agg

  // --- CSR build (hierarchical scan) ---
  zero_int_kernel<<<(N + 255) / 256, 256, 0, stream>>>(counts, N);
  hist_kernel<<<(Etot + 255) / 256, 256, 0, stream>>>(ei, E, N, counts);
  scan1_kernel<<<NB, 256, 0, stream>>>(counts, blocksums, N);
  scan2_kernel<<<1, 64, 0, stream>>>(blocksums, blockoff, NB);
  scan3_kernel<<<NB, 256, 0, stream>>>(counts, blockoff, indptr, fillpos, N);
  fill_kernel<<<(Etot + 255) / 256, 256, 0, stream>>>(ei, E, N, fillpos, srcs);

  // --- Conversions ---
  int n8 = N * C1 / 8;
  convx_kernel<<<(n8 + 255) / 256, 256, 0, stream>>>(x, xb, n8);
  convwt_kernel<<<(256 * 256 + 255) / 256, 256, 0, stream>>>(W1, W1t, 256, C1);
  convwt_kernel<<<(256 * 64 + 255) / 256, 256, 0, stream>>>(W2, W2t, 256, HID);

  // --- Layer 1 ---
  gemm_bf16_kernel<<<dim3((N + 63) / 64, C1 / 64), 256, 0, stream>>>(xb, W1t, H1b, N, C1, IN_DIM);
  alpha1_kernel<<<(N + 3) / 4, 256, 0, stream>>>(H1b, a_src1, a_dst1, asrc1, adst1, N);
  gat1_agg<<<(N + 3) / 4, 256, 0, stream>>>(H1b, asrc1, adst1, indptr, srcs,
                                            b1, g1, be1, mu1, var1, X2b, N);

  // --- Layer 2 ---
  gemm_bf16_kernel<<<dim3((N + 63) / 64, HID / 64), 256, 0, stream>>>(X2b, W2t, H2b, N, HID, C1);
  alpha2_kernel<<<(N + 3) / 4, 256, 0, stream>>>(H2b, a_src2, a_dst2, asrc2, adst2, N);
  gat2_agg<<<(N + 3) / 4, 256, 0, stream>>>(H2b, asrc2, adst2, indptr, srcs,
                                            b2, g2, be2, mu2, var2, out, N);
}